// Round 1
// baseline (1102.335 us; speedup 1.0000x reference)
//
#include <hip/hip_runtime.h>
#include <math.h>

// Problem constants (match reference)
constexpr int C  = 128;
constexpr int K  = 16;
constexpr int H  = 128;
constexpr int PB = 16;   // points per block
constexpr int PH = 8;    // points per 128-thread half
constexpr int INS = 388; // 385 rounded up to multiple of 4 (float4 LDS reads)
constexpr int NB2 = 256; // blocks for point-stat partial reduction

__device__ __forceinline__ float gelu_exact(float v) {
    return 0.5f * v * (1.0f + erff(v * 0.70710678118654752440f));
}
__device__ __forceinline__ float sigmoidf(float v) {
    return 1.0f / (1.0f + __expf(-v));
}

// ---------------------------------------------------------------------------
// Kernel 1: LayerNorm. One wave per point; lane handles cols {lane, lane+64}.
// ---------------------------------------------------------------------------
__global__ __launch_bounds__(256) void ln_kernel(
    const float* __restrict__ feats, const float* __restrict__ g,
    const float* __restrict__ b, float* __restrict__ x, int n)
{
    const int lane = threadIdx.x & 63;
    const int wave = threadIdx.x >> 6;
    const int i = blockIdx.x * 4 + wave;
    if (i >= n) return;
    const float f0 = feats[i * C + lane];
    const float f1 = feats[i * C + 64 + lane];
    float s = f0 + f1;
    #pragma unroll
    for (int o = 32; o > 0; o >>= 1) s += __shfl_xor(s, o, 64);
    const float mu = s * (1.0f / C);
    const float d0 = f0 - mu, d1 = f1 - mu;
    float v = d0 * d0 + d1 * d1;
    #pragma unroll
    for (int o = 32; o > 0; o >>= 1) v += __shfl_xor(v, o, 64);
    const float rs = rsqrtf(v * (1.0f / C) + 1e-5f);
    x[i * C + lane]      = d0 * rs * g[lane]      + b[lane];
    x[i * C + 64 + lane] = d1 * rs * g[64 + lane] + b[64 + lane];
}

// ---------------------------------------------------------------------------
// Kernel 2a/2b: global point stats (mean over N, then scale = max|p - mean|)
// computed as {sum, min, max} per coordinate in one pass, two-stage reduce.
// partial layout: [block][9] = {sum0..2, min0..2, max0..2}; stats = {mean0..2, scale0..2}
// ---------------------------------------------------------------------------
__global__ __launch_bounds__(256) void pstat_partial(
    const float* __restrict__ pts, float* __restrict__ partial, int n)
{
    __shared__ float sm[256];
    const int tid = threadIdx.x;
    float s[3] = {0, 0, 0};
    float mn[3] = {1e30f, 1e30f, 1e30f};
    float mx[3] = {-1e30f, -1e30f, -1e30f};
    for (int i = blockIdx.x * blockDim.x + tid; i < n; i += gridDim.x * blockDim.x) {
        #pragma unroll
        for (int c = 0; c < 3; ++c) {
            float v = pts[i * 3 + c];
            s[c] += v; mn[c] = fminf(mn[c], v); mx[c] = fmaxf(mx[c], v);
        }
    }
    for (int q = 0; q < 9; ++q) {
        float v = (q < 3) ? s[q] : (q < 6) ? mn[q - 3] : mx[q - 6];
        sm[tid] = v;
        __syncthreads();
        for (int o = 128; o > 0; o >>= 1) {
            if (tid < o) {
                float a = sm[tid], c = sm[tid + o];
                sm[tid] = (q < 3) ? a + c : (q < 6) ? fminf(a, c) : fmaxf(a, c);
            }
            __syncthreads();
        }
        if (tid == 0) partial[blockIdx.x * 9 + q] = sm[0];
        __syncthreads();
    }
}

__global__ __launch_bounds__(256) void pstat_final(
    const float* __restrict__ partial, float* __restrict__ stats, int n)
{
    __shared__ float sm[256];
    const int tid = threadIdx.x;
    for (int q = 0; q < 9; ++q) {
        float v = partial[tid * 9 + q];
        sm[tid] = v;
        __syncthreads();
        for (int o = 128; o > 0; o >>= 1) {
            if (tid < o) {
                float a = sm[tid], c = sm[tid + o];
                sm[tid] = (q < 3) ? a + c : (q < 6) ? fminf(a, c) : fmaxf(a, c);
            }
            __syncthreads();
        }
        if (tid == 0) sm[q] = sm[0];   // park result q in sm[0..8] (safe: q <= current slot)
        __syncthreads();
    }
    if (tid < 3) {
        float mean = sm[tid] / (float)n;
        float mnv = sm[3 + tid], mxv = sm[6 + tid];
        float scale = fmaxf(fmaxf(mxv - mean, mean - mnv), 1e-6f);
        stats[tid] = mean;
        stats[3 + tid] = scale;
    }
}

// ---------------------------------------------------------------------------
// Kernel 3: the heavy fused per-point stage.
// 256 threads = 2 halves x 128; each half owns 8 points. jj = output index.
// LDS input vector per point: [x(128) | mean_feat(128) | boundary(1) | coord_embed(128)]
// ---------------------------------------------------------------------------
__device__ __forceinline__ float half_reduce(float v, int wave, volatile float* red)
{
    #pragma unroll
    for (int o = 32; o > 0; o >>= 1) v += __shfl_xor(v, o, 64);
    if ((threadIdx.x & 63) == 0) red[wave] = v;
    __syncthreads();
    float r = red[wave & 2] + red[(wave & 2) | 1];
    __syncthreads();
    return r;
}

__global__ __launch_bounds__(256) void main_kernel(
    const float* __restrict__ x, const float* __restrict__ feats,
    const float* __restrict__ points, const int* __restrict__ neighbors,
    const float* __restrict__ stats,
    const float* __restrict__ cp_w1, const float* __restrict__ cp_b1,
    const float* __restrict__ cp_w2, const float* __restrict__ cp_b2,
    const float* __restrict__ bd_w1, const float* __restrict__ bd_b1,
    const float* __restrict__ bd_w2, const float* __restrict__ bd_b2,
    const float* __restrict__ mix_w1, const float* __restrict__ mix_b1,
    const float* __restrict__ mix_w2, const float* __restrict__ mix_b2,
    const float* __restrict__ gate_w1, const float* __restrict__ gate_b1,
    const float* __restrict__ gate_w2, const float* __restrict__ gate_b2,
    const float* __restrict__ out_w, const float* __restrict__ out_b,
    float* __restrict__ out, int n)
{
    __shared__ float in_s[PB * INS];
    __shared__ float h_s[PB * C];
    __shared__ int   nb_s[PB * K];
    __shared__ float val_s[PB * K];
    __shared__ float mpp[PB * K * 3];
    __shared__ float mp_s[PB * 3];
    __shared__ float pts_s[PB * 3];
    __shared__ float denom_s[PB], cd_s[PB], fd_s[PB];
    __shared__ float red[4];

    const int tid  = threadIdx.x;
    const int jj   = tid & 127;
    const int half = tid >> 7;
    const int wave = tid >> 6;
    const int i0   = blockIdx.x * PB;

    // ---- neighbor load + validity (256 threads cover 16 pts x 16 nbrs) ----
    {
        int p = tid >> 4, k = tid & 15;
        int i = i0 + p;
        int nb = (i < n) ? neighbors[i * K + k] : -1;
        int v = (nb >= 0 && nb < n) ? 1 : 0;
        nb_s[p * K + k]  = v ? nb : 0;
        val_s[p * K + k] = (float)v;
    }
    // ---- x into LDS ----
    #pragma unroll
    for (int pl = 0; pl < PH; ++pl) {
        int p = half * PH + pl, i = i0 + p;
        in_s[p * INS + jj] = (i < n) ? x[i * C + jj] : 0.0f;
    }
    __syncthreads();

    // ---- denom, neighbor-point staging ----
    if (tid < PB) {
        float c = 0;
        #pragma unroll
        for (int k = 0; k < K; ++k) c += val_s[tid * K + k];
        denom_s[tid] = fmaxf(c, 1.0f);
    }
    {
        int p = tid >> 4, k = tid & 15;
        float v = val_s[p * K + k];
        int nb = nb_s[p * K + k];
        float a = 0, b = 0, c = 0;
        if (v > 0.0f) { a = points[nb * 3]; b = points[nb * 3 + 1]; c = points[nb * 3 + 2]; }
        mpp[(p * K + k) * 3 + 0] = a;
        mpp[(p * K + k) * 3 + 1] = b;
        mpp[(p * K + k) * 3 + 2] = c;
    }
    __syncthreads();

    // ---- mean_feat (gather) ----
    #pragma unroll
    for (int pl = 0; pl < PH; ++pl) {
        int p = half * PH + pl;
        float acc = 0;
        #pragma unroll
        for (int k = 0; k < K; ++k) {
            if (val_s[p * K + k] > 0.0f) acc += x[nb_s[p * K + k] * C + jj];
        }
        in_s[p * INS + C + jj] = acc / denom_s[p];
    }
    // ---- mean_point + normalized point coords ----
    if (tid < PB * 3) {
        int p = tid / 3, c = tid % 3, i = i0 + p;
        float s = 0;
        for (int k = 0; k < K; ++k) s += mpp[(p * K + k) * 3 + c];
        mp_s[p * 3 + c] = s / denom_s[p];
        float pv = (i < n) ? points[i * 3 + c] : 0.0f;
        pts_s[p * 3 + c] = (pv - stats[c]) / stats[3 + c];
    }
    __syncthreads();

    // ---- coord_diff ----
    if (tid < PB) {
        int i = i0 + tid;
        float s = 0;
        #pragma unroll
        for (int c = 0; c < 3; ++c) {
            float pv = (i < n) ? points[i * 3 + c] : 0.0f;
            float d = pv - mp_s[tid * 3 + c];
            s += d * d;
        }
        cd_s[tid] = sqrtf(s);
    }
    // ---- feat_diff (needs block participation for reduction) ----
    #pragma unroll
    for (int pl = 0; pl < PH; ++pl) {
        int p = half * PH + pl;
        float d = in_s[p * INS + jj] - in_s[p * INS + C + jj];
        float r = half_reduce(d * d, wave, red);
        if (jj == 0) fd_s[p] = sqrtf(r);
    }
    __syncthreads();

    // ---- boundary MLP (2 -> H -> 1), sigmoid ----
    {
        const float wf = bd_w1[jj], wc = bd_w1[H + jj];
        const float b1 = bd_b1[jj], w2 = bd_w2[jj], b2 = bd_b2[0];
        #pragma unroll
        for (int pl = 0; pl < PH; ++pl) {
            int p = half * PH + pl;
            float hb = gelu_exact(fd_s[p] * wf + cd_s[p] * wc + b1);
            float r = half_reduce(hb * w2, wave, red);
            if (jj == 0) in_s[p * INS + 2 * C] = sigmoidf(r + b2);
        }
    }

    // ---- coord_embed hidden (3 -> H) ----
    {
        const float w0 = cp_w1[jj], w1 = cp_w1[H + jj], w2 = cp_w1[2 * H + jj];
        const float b1 = cp_b1[jj];
        #pragma unroll
        for (int pl = 0; pl < PH; ++pl) {
            int p = half * PH + pl;
            float h = b1 + pts_s[p * 3] * w0 + pts_s[p * 3 + 1] * w1 + pts_s[p * 3 + 2] * w2;
            h_s[p * C + jj] = gelu_exact(h);
        }
    }
    __syncthreads();

    // ---- coord_embed output (H -> C) into input vector ----
    {
        float acc[PH];
        const float b2 = cp_b2[jj];
        #pragma unroll
        for (int pl = 0; pl < PH; ++pl) acc[pl] = b2;
        for (int q = 0; q < C / 4; ++q) {
            const float w0 = cp_w2[(4 * q + 0) * C + jj];
            const float w1 = cp_w2[(4 * q + 1) * C + jj];
            const float w2 = cp_w2[(4 * q + 2) * C + jj];
            const float w3 = cp_w2[(4 * q + 3) * C + jj];
            #pragma unroll
            for (int pl = 0; pl < PH; ++pl) {
                int p = half * PH + pl;
                const float4 v = *reinterpret_cast<const float4*>(&h_s[p * C + 4 * q]);
                acc[pl] += v.x * w0 + v.y * w1 + v.z * w2 + v.w * w3;
            }
        }
        #pragma unroll
        for (int pl = 0; pl < PH; ++pl) {
            int p = half * PH + pl;
            in_s[p * INS + 2 * C + 1 + jj] = acc[pl];
        }
    }
    __syncthreads();

    // ---- mix hidden (385 -> H), GELU ----
    {
        float acc[PH];
        const float b1 = mix_b1[jj];
        #pragma unroll
        for (int pl = 0; pl < PH; ++pl) acc[pl] = b1;
        for (int q = 0; q < 96; ++q) {
            const float w0 = mix_w1[(4 * q + 0) * C + jj];
            const float w1 = mix_w1[(4 * q + 1) * C + jj];
            const float w2 = mix_w1[(4 * q + 2) * C + jj];
            const float w3 = mix_w1[(4 * q + 3) * C + jj];
            #pragma unroll
            for (int pl = 0; pl < PH; ++pl) {
                int p = half * PH + pl;
                const float4 v = *reinterpret_cast<const float4*>(&in_s[p * INS + 4 * q]);
                acc[pl] += v.x * w0 + v.y * w1 + v.z * w2 + v.w * w3;
            }
        }
        const float wt = mix_w1[384 * C + jj];
        #pragma unroll
        for (int pl = 0; pl < PH; ++pl) {
            int p = half * PH + pl;
            acc[pl] += in_s[p * INS + 384] * wt;
        }
        __syncthreads();   // cp-hidden fully consumed; safe to overwrite h_s
        #pragma unroll
        for (int pl = 0; pl < PH; ++pl) {
            int p = half * PH + pl;
            h_s[p * C + jj] = gelu_exact(acc[pl]);
        }
    }
    __syncthreads();

    // ---- refined = mix second layer (H -> C), kept in registers ----
    float refreg[PH];
    {
        const float b2 = mix_b2[jj];
        #pragma unroll
        for (int pl = 0; pl < PH; ++pl) refreg[pl] = b2;
        for (int q = 0; q < C / 4; ++q) {
            const float w0 = mix_w2[(4 * q + 0) * C + jj];
            const float w1 = mix_w2[(4 * q + 1) * C + jj];
            const float w2 = mix_w2[(4 * q + 2) * C + jj];
            const float w3 = mix_w2[(4 * q + 3) * C + jj];
            #pragma unroll
            for (int pl = 0; pl < PH; ++pl) {
                int p = half * PH + pl;
                const float4 v = *reinterpret_cast<const float4*>(&h_s[p * C + 4 * q]);
                refreg[pl] += v.x * w0 + v.y * w1 + v.z * w2 + v.w * w3;
            }
        }
    }

    // ---- gate hidden (257 -> H), GELU ----
    {
        float acc[PH];
        const float b1 = gate_b1[jj];
        #pragma unroll
        for (int pl = 0; pl < PH; ++pl) acc[pl] = b1;
        for (int q = 0; q < 64; ++q) {
            const float w0 = gate_w1[(4 * q + 0) * C + jj];
            const float w1 = gate_w1[(4 * q + 1) * C + jj];
            const float w2 = gate_w1[(4 * q + 2) * C + jj];
            const float w3 = gate_w1[(4 * q + 3) * C + jj];
            #pragma unroll
            for (int pl = 0; pl < PH; ++pl) {
                int p = half * PH + pl;
                const float4 v = *reinterpret_cast<const float4*>(&in_s[p * INS + 4 * q]);
                acc[pl] += v.x * w0 + v.y * w1 + v.z * w2 + v.w * w3;
            }
        }
        const float wt = gate_w1[256 * C + jj];
        #pragma unroll
        for (int pl = 0; pl < PH; ++pl) {
            int p = half * PH + pl;
            acc[pl] += in_s[p * INS + 2 * C] * wt;
        }
        __syncthreads();   // mix-hidden fully consumed by refined loop
        #pragma unroll
        for (int pl = 0; pl < PH; ++pl) {
            int p = half * PH + pl;
            h_s[p * C + jj] = gelu_exact(acc[pl]);
        }
    }
    __syncthreads();

    // ---- gate second layer (H -> C), sigmoid, then gr = gate * refined ----
    {
        float acc[PH];
        const float b2 = gate_b2[jj];
        #pragma unroll
        for (int pl = 0; pl < PH; ++pl) acc[pl] = b2;
        for (int q = 0; q < C / 4; ++q) {
            const float w0 = gate_w2[(4 * q + 0) * C + jj];
            const float w1 = gate_w2[(4 * q + 1) * C + jj];
            const float w2 = gate_w2[(4 * q + 2) * C + jj];
            const float w3 = gate_w2[(4 * q + 3) * C + jj];
            #pragma unroll
            for (int pl = 0; pl < PH; ++pl) {
                int p = half * PH + pl;
                const float4 v = *reinterpret_cast<const float4*>(&h_s[p * C + 4 * q]);
                acc[pl] += v.x * w0 + v.y * w1 + v.z * w2 + v.w * w3;
            }
        }
        __syncthreads();   // gate-hidden fully consumed; overwrite h_s with gr
        #pragma unroll
        for (int pl = 0; pl < PH; ++pl) {
            int p = half * PH + pl;
            h_s[p * C + jj] = sigmoidf(acc[pl]) * refreg[pl];
        }
    }
    __syncthreads();

    // ---- out = gr @ out_w + out_b ; final residual add ----
    {
        float acc[PH];
        const float b = out_b[jj];
        #pragma unroll
        for (int pl = 0; pl < PH; ++pl) acc[pl] = b;
        for (int q = 0; q < C / 4; ++q) {
            const float w0 = out_w[(4 * q + 0) * C + jj];
            const float w1 = out_w[(4 * q + 1) * C + jj];
            const float w2 = out_w[(4 * q + 2) * C + jj];
            const float w3 = out_w[(4 * q + 3) * C + jj];
            #pragma unroll
            for (int pl = 0; pl < PH; ++pl) {
                int p = half * PH + pl;
                const float4 v = *reinterpret_cast<const float4*>(&h_s[p * C + 4 * q]);
                acc[pl] += v.x * w0 + v.y * w1 + v.z * w2 + v.w * w3;
            }
        }
        #pragma unroll
        for (int pl = 0; pl < PH; ++pl) {
            int p = half * PH + pl, i = i0 + p;
            if (i < n) out[i * C + jj] = feats[i * C + jj] + acc[pl];
        }
    }
}

// ---------------------------------------------------------------------------
extern "C" void kernel_launch(void* const* d_in, const int* in_sizes, int n_in,
                              void* d_out, int out_size, void* d_ws, size_t ws_size,
                              hipStream_t stream)
{
    const float* feats     = (const float*)d_in[0];
    const float* points    = (const float*)d_in[1];
    const int*   neighbors = (const int*)d_in[2];
    const float* ln_g      = (const float*)d_in[3];
    const float* ln_b      = (const float*)d_in[4];
    const float* cp_w1     = (const float*)d_in[5];
    const float* cp_b1     = (const float*)d_in[6];
    const float* cp_w2     = (const float*)d_in[7];
    const float* cp_b2     = (const float*)d_in[8];
    const float* bd_w1     = (const float*)d_in[9];
    const float* bd_b1     = (const float*)d_in[10];
    const float* bd_w2     = (const float*)d_in[11];
    const float* bd_b2     = (const float*)d_in[12];
    const float* mix_w1    = (const float*)d_in[13];
    const float* mix_b1    = (const float*)d_in[14];
    const float* mix_w2    = (const float*)d_in[15];
    const float* mix_b2    = (const float*)d_in[16];
    const float* gate_w1   = (const float*)d_in[17];
    const float* gate_b1   = (const float*)d_in[18];
    const float* gate_w2   = (const float*)d_in[19];
    const float* gate_b2   = (const float*)d_in[20];
    const float* out_w     = (const float*)d_in[21];
    const float* out_b     = (const float*)d_in[22];
    float* out = (float*)d_out;

    const int n = in_sizes[0] / C;

    // ws layout: x[N*C] | partial[NB2*9] | stats[6]
    float* x       = (float*)d_ws;
    float* partial = x + (size_t)n * C;
    float* stats   = partial + NB2 * 9;

    ln_kernel<<<(n + 3) / 4, 256, 0, stream>>>(feats, ln_g, ln_b, x, n);
    pstat_partial<<<NB2, 256, 0, stream>>>(points, partial, n);
    pstat_final<<<1, 256, 0, stream>>>(partial, stats, n);
    main_kernel<<<(n + PB - 1) / PB, 256, 0, stream>>>(
        x, feats, points, neighbors, stats,
        cp_w1, cp_b1, cp_w2, cp_b2, bd_w1, bd_b1, bd_w2, bd_b2,
        mix_w1, mix_b1, mix_w2, mix_b2, gate_w1, gate_b1, gate_w2, gate_b2,
        out_w, out_b, out, n);
}

// Round 2
// 763.105 us; speedup vs baseline: 1.4445x; 1.4445x over previous
//
#include <hip/hip_runtime.h>
#include <math.h>

// Problem constants
constexpr int C   = 128;
constexpr int K   = 16;
constexpr int NB2 = 256;   // blocks for point-stat partial reduction
constexpr int PB  = 64;    // points per block (main kernel)
constexpr int AS  = 392;   // A-buffer row stride in bf16 elems (384 + 8 pad)

// Packed-weight offsets (bf16 elems) in ws: fragment order
// [(chunk*8 + tile)*64 + lane]*8 + j  per GEMM
constexpr int WT_MIX   = 0;        // K=384 -> 12 chunks
constexpr int WT_GATE  = 49152;    // K=256 -> 8 chunks
constexpr int WT_CP2   = 81920;    // K=128 -> 4 chunks
constexpr int WT_MIX2  = 98304;
constexpr int WT_GATE2 = 114688;
constexpr int WT_OUT   = 131072;
constexpr int WT_TOTAL = 147456;

typedef __attribute__((ext_vector_type(8))) short short8;
typedef __attribute__((ext_vector_type(4))) short short4v;
typedef __attribute__((ext_vector_type(4))) float f32x4;

__device__ __forceinline__ short f2bf(float f) {
    unsigned u = __float_as_uint(f);
    unsigned r = (u + 0x7fffu + ((u >> 16) & 1u)) >> 16;
    return (short)r;
}
__device__ __forceinline__ float bflo(unsigned v) { return __uint_as_float(v << 16); }
__device__ __forceinline__ float bfhi(unsigned v) { return __uint_as_float(v & 0xffff0000u); }
__device__ __forceinline__ float gelu_exact(float v) {
    return 0.5f * v * (1.0f + erff(v * 0.70710678118654752440f));
}
__device__ __forceinline__ float sigm(float v) { return 1.0f / (1.0f + __expf(-v)); }

// ---------------------------------------------------------------------------
// Prep: pack all weights to bf16 in MFMA A-operand fragment order (transposed).
// For GEMM out[p][n] = sum_k act[p][k] W[k][n], packed elem:
//   wt[off + ((c*8+t)*64 + l)*8 + j] = bf16(W[c*32 + (l>>4)*8 + j][t*16 + (l&15)])
// mix skips source row 256 (boundary, handled as rank-1).
// ---------------------------------------------------------------------------
__global__ __launch_bounds__(256) void prep_wt(
    const float* __restrict__ mix_w1, const float* __restrict__ gate_w1,
    const float* __restrict__ cp_w2,  const float* __restrict__ mix_w2,
    const float* __restrict__ gate_w2, const float* __restrict__ out_w,
    short* __restrict__ wt)
{
    int b = blockIdx.x;  // 36 chunks total
    const float* src; int off; int c; bool skip256 = false;
    if (b < 12)      { src = mix_w1;  off = WT_MIX;   c = b;      skip256 = true; }
    else if (b < 20) { src = gate_w1; off = WT_GATE;  c = b - 12; }
    else if (b < 24) { src = cp_w2;   off = WT_CP2;   c = b - 20; }
    else if (b < 28) { src = mix_w2;  off = WT_MIX2;  c = b - 24; }
    else if (b < 32) { src = gate_w2; off = WT_GATE2; c = b - 28; }
    else             { src = out_w;   off = WT_OUT;   c = b - 32; }
    for (int ii = 0; ii < 16; ++ii) {
        int e = ii * 256 + threadIdx.x;   // 0..4095
        int j = e & 7, l = (e >> 3) & 63, t = e >> 9;
        int k = c * 32 + ((l >> 4) * 8) + j;
        int n = t * 16 + (l & 15);
        int kk = (skip256 && k >= 256) ? k + 1 : k;
        wt[off + c * 4096 + e] = f2bf(src[kk * C + n]);
    }
}

// ---------------------------------------------------------------------------
// LayerNorm -> bf16 x table. One wave per point; lane owns cols {2l, 2l+1}.
// ---------------------------------------------------------------------------
__global__ __launch_bounds__(256) void ln_kernel(
    const float* __restrict__ feats, const float* __restrict__ g,
    const float* __restrict__ b, unsigned* __restrict__ xb, int n)
{
    const int lane = threadIdx.x & 63;
    const int wave = threadIdx.x >> 6;
    const int i = blockIdx.x * 4 + wave;
    if (i >= n) return;
    const float2 f = *(const float2*)(feats + i * C + 2 * lane);
    float s = f.x + f.y;
    #pragma unroll
    for (int o = 32; o > 0; o >>= 1) s += __shfl_xor(s, o, 64);
    const float mu = s * (1.0f / C);
    const float d0 = f.x - mu, d1 = f.y - mu;
    float v = d0 * d0 + d1 * d1;
    #pragma unroll
    for (int o = 32; o > 0; o >>= 1) v += __shfl_xor(v, o, 64);
    const float rs = rsqrtf(v * (1.0f / C) + 1e-5f);
    const float x0 = d0 * rs * g[2 * lane] + b[2 * lane];
    const float x1 = d1 * rs * g[2 * lane + 1] + b[2 * lane + 1];
    unsigned pk = (unsigned short)f2bf(x0) | ((unsigned)(unsigned short)f2bf(x1) << 16);
    xb[i * (C / 2) + lane] = pk;
}

// ---------------------------------------------------------------------------
// Point stats (unchanged from round 1)
// ---------------------------------------------------------------------------
__global__ __launch_bounds__(256) void pstat_partial(
    const float* __restrict__ pts, float* __restrict__ partial, int n)
{
    __shared__ float sm[256];
    const int tid = threadIdx.x;
    float s[3] = {0, 0, 0};
    float mn[3] = {1e30f, 1e30f, 1e30f};
    float mx[3] = {-1e30f, -1e30f, -1e30f};
    for (int i = blockIdx.x * blockDim.x + tid; i < n; i += gridDim.x * blockDim.x) {
        #pragma unroll
        for (int c = 0; c < 3; ++c) {
            float v = pts[i * 3 + c];
            s[c] += v; mn[c] = fminf(mn[c], v); mx[c] = fmaxf(mx[c], v);
        }
    }
    for (int q = 0; q < 9; ++q) {
        float v = (q < 3) ? s[q] : (q < 6) ? mn[q - 3] : mx[q - 6];
        sm[tid] = v;
        __syncthreads();
        for (int o = 128; o > 0; o >>= 1) {
            if (tid < o) {
                float a = sm[tid], c = sm[tid + o];
                sm[tid] = (q < 3) ? a + c : (q < 6) ? fminf(a, c) : fmaxf(a, c);
            }
            __syncthreads();
        }
        if (tid == 0) partial[blockIdx.x * 9 + q] = sm[0];
        __syncthreads();
    }
}

__global__ __launch_bounds__(256) void pstat_final(
    const float* __restrict__ partial, float* __restrict__ stats, int n)
{
    __shared__ float sm[256];
    const int tid = threadIdx.x;
    for (int q = 0; q < 9; ++q) {
        float v = partial[tid * 9 + q];
        sm[tid] = v;
        __syncthreads();
        for (int o = 128; o > 0; o >>= 1) {
            if (tid < o) {
                float a = sm[tid], c = sm[tid + o];
                sm[tid] = (q < 3) ? a + c : (q < 6) ? fminf(a, c) : fmaxf(a, c);
            }
            __syncthreads();
        }
        if (tid == 0) sm[q] = sm[0];
        __syncthreads();
    }
    if (tid < 3) {
        float mean = sm[tid] / (float)n;
        float scale = fmaxf(fmaxf(sm[6 + tid] - mean, mean - sm[3 + tid]), 1e-6f);
        stats[tid] = mean;
        stats[3 + tid] = scale;
    }
}

// ---------------------------------------------------------------------------
// MFMA GEMM helper: 8 N-tiles x NC K-chunks, acc[t] = D^T tiles.
// act_row points at (A-region base + prow*AS + colOff) for this lane's point.
// ---------------------------------------------------------------------------
template<int NC>
__device__ __forceinline__ void gemm_mm(const short* __restrict__ act_row,
                                        const short* __restrict__ wtg,
                                        int lane, f32x4 acc[8])
{
    const int koff = (lane >> 4) * 8;
    #pragma unroll
    for (int c = 0; c < NC; ++c) {
        short8 af = *(const short8*)(act_row + c * 32 + koff);
        const short* wc = wtg + c * 4096 + lane * 8;
        #pragma unroll
        for (int t = 0; t < 8; ++t) {
            short8 wf = *(const short8*)(wc + t * 512);
            acc[t] = __builtin_amdgcn_mfma_f32_16x16x32_bf16(wf, af, acc[t], 0, 0, 0);
        }
    }
}

// ---------------------------------------------------------------------------
// Main fused kernel. 256 threads = 4 waves; 64 points/block.
// A-buffer bf16 [64][AS]: cols 0..127 = x, 128..255 = mean_feat,
// cols 256..383 = (ce -> mix hidden -> gate hidden -> gr), later reused as
// f32 out staging [64][132].
// ---------------------------------------------------------------------------
__global__ __launch_bounds__(256, 2) void main_kernel(
    const unsigned* __restrict__ xb, const float* __restrict__ feats,
    const float* __restrict__ points, const int* __restrict__ neighbors,
    const float* __restrict__ stats, const short* __restrict__ wt,
    const float* __restrict__ cp_w1, const float* __restrict__ cp_b1,
    const float* __restrict__ cp_b2,
    const float* __restrict__ bd_w1, const float* __restrict__ bd_b1,
    const float* __restrict__ bd_w2, const float* __restrict__ bd_b2,
    const float* __restrict__ mix_w1, const float* __restrict__ mix_b1,
    const float* __restrict__ mix_b2,
    const float* __restrict__ gate_w1, const float* __restrict__ gate_b1,
    const float* __restrict__ gate_b2,
    const float* __restrict__ out_b,
    float* __restrict__ out, int n)
{
    __shared__ __align__(16) short A_s[PB * AS];   // 50176 B
    __shared__ int   nb_s[PB * K];                 // 4096 B
    __shared__ float mp_s[PB * 4];
    __shared__ float pts_s[PB * 4];
    __shared__ float fd_s[PB], cd_s[PB], bd_s[PB];
    __shared__ float bdp_s[256];

    const int tid  = threadIdx.x;
    const int lane = tid & 63;
    const int w    = tid >> 6;
    const int i0   = blockIdx.x * PB;
    const int m16  = lane & 15;         // point-within-tile (D column)
    const int h4   = lane >> 4;         // quad index
    const int prow = w * 16 + m16;      // this lane's point row for GEMMs

    // ---- P0: neighbors + x rows into LDS ----
    #pragma unroll
    for (int ii = 0; ii < 4; ++ii) {
        int idx = ii * 256 + tid;           // 0..1023
        int p = idx >> 4, k = idx & 15, i = i0 + p;
        int nb = (i < n) ? neighbors[i * K + k] : -1;
        nb_s[idx] = (nb >= 0 && nb < n) ? nb : -1;
    }
    #pragma unroll
    for (int ii = 0; ii < 4; ++ii) {
        int idx = ii * 256 + tid;           // 0..1023, 16B chunks
        int p = idx >> 4, s = idx & 15, i = i0 + p;
        uint4 v = make_uint4(0, 0, 0, 0);
        if (i < n) v = *(const uint4*)(xb + i * (C / 2) + s * 4);
        *(uint4*)&A_s[p * AS + s * 8] = v;
    }
    __syncthreads();  // S1

    // ---- P1: gather mean_feat + mean_point + feat_diff (per wave, 16 pts) ----
    for (int pl = 0; pl < 16; ++pl) {
        int p = pl * 4 + w;
        float fx = 0.0f, fy = 0.0f, mpacc = 0.0f;
        int cnt = 0;
        for (int k = 0; k < K; ++k) {
            int nb = nb_s[p * K + k];
            if (nb >= 0) {
                ++cnt;
                unsigned v = xb[nb * (C / 2) + lane];
                fx += bflo(v); fy += bfhi(v);
                if (lane < 3) mpacc += points[nb * 3 + lane];
            }
        }
        float denom = fmaxf((float)cnt, 1.0f);
        float mfx = fx / denom, mfy = fy / denom;
        unsigned pk = (unsigned short)f2bf(mfx) | ((unsigned)(unsigned short)f2bf(mfy) << 16);
        *(unsigned*)&A_s[p * AS + C + lane * 2] = pk;
        if (lane < 3) mp_s[p * 4 + lane] = mpacc / denom;
        unsigned xv = *(const unsigned*)&A_s[p * AS + lane * 2];
        float dx = bflo(xv) - mfx, dy = bfhi(xv) - mfy;
        float ss = dx * dx + dy * dy;
        #pragma unroll
        for (int o = 32; o > 0; o >>= 1) ss += __shfl_xor(ss, o, 64);
        if (lane == 0) fd_s[p] = sqrtf(ss);
    }
    __syncthreads();  // S2

    // ---- P2: coord_diff + normalized coords (64 threads) ----
    if (tid < PB) {
        int i = i0 + tid;
        float s = 0.0f;
        #pragma unroll
        for (int c = 0; c < 3; ++c) {
            float pv = (i < n) ? points[i * 3 + c] : 0.0f;
            float d = pv - mp_s[tid * 4 + c];
            s += d * d;
            pts_s[tid * 4 + c] = (pv - stats[c]) / stats[3 + c];
        }
        cd_s[tid] = sqrtf(s);
    }
    __syncthreads();  // S3

    // ---- P3: boundary MLP partials (all 256 threads; 32 hidden each) ----
    {
        int p = tid >> 2, q = tid & 3;
        float fd = fd_s[p], cd = cd_s[p];
        float s = 0.0f;
        for (int h = q * 32; h < q * 32 + 32; ++h)
            s += gelu_exact(fd * bd_w1[h] + cd * bd_w1[C + h] + bd_b1[h]) * bd_w2[h];
        bdp_s[tid] = s;
    }
    __syncthreads();  // S4

    // ---- P4: finalize boundary; coord hidden in regs; cp2 GEMM -> ce ----
    if (tid < PB)
        bd_s[tid] = sigm(bdp_s[tid * 4] + bdp_s[tid * 4 + 1] + bdp_s[tid * 4 + 2] +
                         bdp_s[tid * 4 + 3] + bd_b2[0]);
    {
        float px = pts_s[prow * 4], py = pts_s[prow * 4 + 1], pz = pts_s[prow * 4 + 2];
        f32x4 acc[8];
        #pragma unroll
        for (int t = 0; t < 8; ++t) acc[t] = (f32x4)0.0f;
        #pragma unroll
        for (int c = 0; c < 4; ++c) {
            short8 af;
            #pragma unroll
            for (int j = 0; j < 8; ++j) {
                int hh = c * 32 + h4 * 8 + j;
                float hv = cp_b1[hh] + px * cp_w1[hh] + py * cp_w1[C + hh] + pz * cp_w1[2 * C + hh];
                af[j] = f2bf(gelu_exact(hv));
            }
            const short* wc = wt + WT_CP2 + c * 4096 + lane * 8;
            #pragma unroll
            for (int t = 0; t < 8; ++t) {
                short8 wf = *(const short8*)(wc + t * 512);
                acc[t] = __builtin_amdgcn_mfma_f32_16x16x32_bf16(wf, af, acc[t], 0, 0, 0);
            }
        }
        #pragma unroll
        for (int t = 0; t < 8; ++t) {
            f32x4 b = *(const f32x4*)(cp_b2 + t * 16 + h4 * 4);
            f32x4 v = acc[t] + b;
            short4v pk;
            #pragma unroll
            for (int r = 0; r < 4; ++r) pk[r] = f2bf(v[r]);
            *(short4v*)&A_s[prow * AS + 256 + t * 16 + h4 * 4] = pk;
        }
    }
    __syncthreads();  // S5: ce + bd_s ready

    // ---- P5: mix1 (K=384) + rank-1 boundary + bias, GELU -> hidden ----
    f32x4 macc[8];
    {
        #pragma unroll
        for (int t = 0; t < 8; ++t) macc[t] = (f32x4)0.0f;
        gemm_mm<12>(A_s + prow * AS, wt + WT_MIX, lane, macc);
    }
    __syncthreads();  // S6: all mix1 reads of A done
    {
        float bp = bd_s[prow];
        #pragma unroll
        for (int t = 0; t < 8; ++t) {
            f32x4 wb = *(const f32x4*)(mix_w1 + 256 * C + t * 16 + h4 * 4);
            f32x4 bb = *(const f32x4*)(mix_b1 + t * 16 + h4 * 4);
            f32x4 v = macc[t] + bp * wb + bb;
            short4v pk;
            #pragma unroll
            for (int r = 0; r < 4; ++r) pk[r] = f2bf(gelu_exact(v[r]));
            *(short4v*)&A_s[prow * AS + 256 + t * 16 + h4 * 4] = pk;
        }
    }
    __syncthreads();  // S7: mix hidden ready

    // ---- P6: mix2 -> refined (regs) ----
    f32x4 refined[8];
    {
        #pragma unroll
        for (int t = 0; t < 8; ++t) refined[t] = (f32x4)0.0f;
        gemm_mm<4>(A_s + prow * AS + 256, wt + WT_MIX2, lane, refined);
        #pragma unroll
        for (int t = 0; t < 8; ++t)
            refined[t] += *(const f32x4*)(mix_b2 + t * 16 + h4 * 4);
    }
    __syncthreads();  // S8: all mix2 reads done

    // ---- P7: gate1 (K=256) + rank-1 + bias, GELU -> hidden ----
    {
        f32x4 gacc[8];
        #pragma unroll
        for (int t = 0; t < 8; ++t) gacc[t] = (f32x4)0.0f;
        gemm_mm<8>(A_s + prow * AS, wt + WT_GATE, lane, gacc);
        float bp = bd_s[prow];
        #pragma unroll
        for (int t = 0; t < 8; ++t) {
            f32x4 wb = *(const f32x4*)(gate_w1 + 256 * C + t * 16 + h4 * 4);
            f32x4 bb = *(const f32x4*)(gate_b1 + t * 16 + h4 * 4);
            f32x4 v = gacc[t] + bp * wb + bb;
            short4v pk;
            #pragma unroll
            for (int r = 0; r < 4; ++r) pk[r] = f2bf(gelu_exact(v[r]));
            *(short4v*)&A_s[prow * AS + 256 + t * 16 + h4 * 4] = pk;
        }
    }
    __syncthreads();  // S9: gate hidden ready

    // ---- P8: gate2 -> sigmoid * refined -> gr ----
    {
        f32x4 gacc[8];
        #pragma unroll
        for (int t = 0; t < 8; ++t) gacc[t] = (f32x4)0.0f;
        gemm_mm<4>(A_s + prow * AS + 256, wt + WT_GATE2, lane, gacc);
        __syncthreads();  // S10: all gate2 reads done
        #pragma unroll
        for (int t = 0; t < 8; ++t) {
            f32x4 bb = *(const f32x4*)(gate_b2 + t * 16 + h4 * 4);
            short4v pk;
            #pragma unroll
            for (int r = 0; r < 4; ++r)
                pk[r] = f2bf(sigm(gacc[t][r] + bb[r]) * refined[t][r]);
            *(short4v*)&A_s[prow * AS + 256 + t * 16 + h4 * 4] = pk;
        }
    }
    __syncthreads();  // S11: gr ready

    // ---- P9: out GEMM + bias -> f32 staging (reuse A region) ----
    float* out_s = (float*)A_s;  // [64][132] f32 = 33792 B
    {
        f32x4 oacc[8];
        #pragma unroll
        for (int t = 0; t < 8; ++t) oacc[t] = (f32x4)0.0f;
        gemm_mm<4>(A_s + prow * AS + 256, wt + WT_OUT, lane, oacc);
        #pragma unroll
        for (int t = 0; t < 8; ++t)
            oacc[t] += *(const f32x4*)(out_b + t * 16 + h4 * 4);
        __syncthreads();  // S12: all reads done before f32 overwrite
        #pragma unroll
        for (int t = 0; t < 8; ++t)
            *(f32x4*)(out_s + prow * 132 + t * 16 + h4 * 4) = oacc[t];
    }
    __syncthreads();  // S13

    // ---- P10: residual add + coalesced store ----
    #pragma unroll
    for (int ii = 0; ii < 8; ++ii) {
        int idx = ii * 256 + tid;          // 0..2047
        int p = idx >> 5, q = idx & 31, i = i0 + p;
        if (i < n) {
            f32x4 v = *(const f32x4*)(out_s + p * 132 + q * 4);
            f32x4 f = *(const f32x4*)(feats + (size_t)i * C + q * 4);
            *(f32x4*)(out + (size_t)i * C + q * 4) = v + f;
        }
    }
}

// ---------------------------------------------------------------------------
extern "C" void kernel_launch(void* const* d_in, const int* in_sizes, int n_in,
                              void* d_out, int out_size, void* d_ws, size_t ws_size,
                              hipStream_t stream)
{
    const float* feats     = (const float*)d_in[0];
    const float* points    = (const float*)d_in[1];
    const int*   neighbors = (const int*)d_in[2];
    const float* ln_g      = (const float*)d_in[3];
    const float* ln_b      = (const float*)d_in[4];
    const float* cp_w1     = (const float*)d_in[5];
    const float* cp_b1     = (const float*)d_in[6];
    const float* cp_w2     = (const float*)d_in[7];
    const float* cp_b2     = (const float*)d_in[8];
    const float* bd_w1     = (const float*)d_in[9];
    const float* bd_b1     = (const float*)d_in[10];
    const float* bd_w2     = (const float*)d_in[11];
    const float* bd_b2     = (const float*)d_in[12];
    const float* mix_w1    = (const float*)d_in[13];
    const float* mix_b1    = (const float*)d_in[14];
    const float* mix_w2    = (const float*)d_in[15];
    const float* mix_b2    = (const float*)d_in[16];
    const float* gate_w1   = (const float*)d_in[17];
    const float* gate_b1   = (const float*)d_in[18];
    const float* gate_w2   = (const float*)d_in[19];
    const float* gate_b2   = (const float*)d_in[20];
    const float* out_w     = (const float*)d_in[21];
    const float* out_b     = (const float*)d_in[22];
    float* out = (float*)d_out;
    (void)n_in; (void)out_size; (void)ws_size;

    const int n = in_sizes[0] / C;

    // ws layout: xb bf16[N*C] | wt bf16[WT_TOTAL] | partial f32[NB2*9] | stats f32[6]
    char* base = (char*)d_ws;
    unsigned* xb   = (unsigned*)base;                       // read as uint pairs
    short* wt      = (short*)(base + (size_t)n * C * 2);
    float* partial = (float*)(base + (size_t)n * C * 2 + WT_TOTAL * 2);
    float* stats   = partial + NB2 * 9;

    prep_wt<<<36, 256, 0, stream>>>(mix_w1, gate_w1, cp_w2, mix_w2, gate_w2, out_w, wt);
    ln_kernel<<<(n + 3) / 4, 256, 0, stream>>>(feats, ln_g, ln_b, xb, n);
    pstat_partial<<<NB2, 256, 0, stream>>>(points, partial, n);
    pstat_final<<<1, 256, 0, stream>>>(partial, stats, n);
    main_kernel<<<(n + PB - 1) / PB, 256, 0, stream>>>(
        xb, feats, points, neighbors, stats, wt,
        cp_w1, cp_b1, cp_b2, bd_w1, bd_b1, bd_w2, bd_b2,
        mix_w1, mix_b1, mix_b2, gate_w1, gate_b1, gate_b2,
        out_b, out, n);
}

// Round 3
// 399.190 us; speedup vs baseline: 2.7614x; 1.9116x over previous
//
#include <hip/hip_runtime.h>
#include <math.h>

// Problem constants
constexpr int C   = 128;
constexpr int K   = 16;
constexpr int H   = 128;
constexpr int NB2 = 256;   // blocks for point-stat partial reduction
constexpr int PB  = 64;    // points per block (main kernel)
constexpr int HS  = 136;   // hidden row stride in bf16 elems (128 + 8 pad)

// Packed-weight offsets (bf16 elems) in ws: fragment order
constexpr int WT_MIX   = 0;        // K=384 -> 12 chunks
constexpr int WT_GATE  = 49152;    // K=256 -> 8 chunks
constexpr int WT_CP2   = 81920;    // K=128 -> 4 chunks
constexpr int WT_MIX2  = 98304;
constexpr int WT_GATE2 = 114688;
constexpr int WT_OUT   = 131072;
constexpr int WT_TOTAL = 147456;

typedef __attribute__((ext_vector_type(8))) short short8;
typedef __attribute__((ext_vector_type(4))) short short4v;
typedef __attribute__((ext_vector_type(4))) float f32x4;

__device__ __forceinline__ short f2bf(float f) {
    unsigned u = __float_as_uint(f);
    unsigned r = (u + 0x7fffu + ((u >> 16) & 1u)) >> 16;
    return (short)r;
}
__device__ __forceinline__ float bflo(unsigned v) { return __uint_as_float(v << 16); }
__device__ __forceinline__ float bfhi(unsigned v) { return __uint_as_float(v & 0xffff0000u); }
__device__ __forceinline__ float gelu_exact(float v) {
    return 0.5f * v * (1.0f + erff(v * 0.70710678118654752440f));
}
__device__ __forceinline__ float sigm(float v) { return 1.0f / (1.0f + __expf(-v)); }

// ---------------------------------------------------------------------------
// Prep: pack weights to bf16 MFMA A-operand fragment order (transposed).
//   wt[off + c*4096 + (t*64 + l)*8 + j] = bf16(W[c*32 + (l>>4)*8 + j][t*16 + (l&15)])
// mix skips source row 256 (boundary column, applied as rank-1 in epilogue).
// ---------------------------------------------------------------------------
__global__ __launch_bounds__(256) void prep_wt(
    const float* __restrict__ mix_w1, const float* __restrict__ gate_w1,
    const float* __restrict__ cp_w2,  const float* __restrict__ mix_w2,
    const float* __restrict__ gate_w2, const float* __restrict__ out_w,
    short* __restrict__ wt)
{
    int b = blockIdx.x;  // 36 chunks total
    const float* src; int off; int c; bool skip256 = false;
    if (b < 12)      { src = mix_w1;  off = WT_MIX;   c = b;      skip256 = true; }
    else if (b < 20) { src = gate_w1; off = WT_GATE;  c = b - 12; }
    else if (b < 24) { src = cp_w2;   off = WT_CP2;   c = b - 20; }
    else if (b < 28) { src = mix_w2;  off = WT_MIX2;  c = b - 24; }
    else if (b < 32) { src = gate_w2; off = WT_GATE2; c = b - 28; }
    else             { src = out_w;   off = WT_OUT;   c = b - 32; }
    for (int ii = 0; ii < 16; ++ii) {
        int e = ii * 256 + threadIdx.x;   // 0..4095
        int j = e & 7, l = (e >> 3) & 63, t = e >> 9;
        int k = c * 32 + ((l >> 4) * 8) + j;
        int n = t * 16 + (l & 15);
        int kk = (skip256 && k >= 256) ? k + 1 : k;
        wt[off + c * 4096 + e] = f2bf(src[kk * C + n]);
    }
}

// ---------------------------------------------------------------------------
// LayerNorm -> packed bf16 x table. One wave per point.
// ---------------------------------------------------------------------------
__global__ __launch_bounds__(256) void ln_kernel(
    const float* __restrict__ feats, const float* __restrict__ g,
    const float* __restrict__ b, unsigned* __restrict__ xb, int n)
{
    const int lane = threadIdx.x & 63;
    const int wave = threadIdx.x >> 6;
    const int i = blockIdx.x * 4 + wave;
    if (i >= n) return;
    const float2 f = *(const float2*)(feats + i * C + 2 * lane);
    float s = f.x + f.y;
    #pragma unroll
    for (int o = 32; o > 0; o >>= 1) s += __shfl_xor(s, o, 64);
    const float mu = s * (1.0f / C);
    const float d0 = f.x - mu, d1 = f.y - mu;
    float v = d0 * d0 + d1 * d1;
    #pragma unroll
    for (int o = 32; o > 0; o >>= 1) v += __shfl_xor(v, o, 64);
    const float rs = rsqrtf(v * (1.0f / C) + 1e-5f);
    const float x0 = d0 * rs * g[2 * lane] + b[2 * lane];
    const float x1 = d1 * rs * g[2 * lane + 1] + b[2 * lane + 1];
    unsigned pk = (unsigned short)f2bf(x0) | ((unsigned)(unsigned short)f2bf(x1) << 16);
    xb[i * (C / 2) + lane] = pk;
}

// ---------------------------------------------------------------------------
// Point stats
// ---------------------------------------------------------------------------
__global__ __launch_bounds__(256) void pstat_partial(
    const float* __restrict__ pts, float* __restrict__ partial, int n)
{
    __shared__ float sm[256];
    const int tid = threadIdx.x;
    float s[3] = {0, 0, 0};
    float mn[3] = {1e30f, 1e30f, 1e30f};
    float mx[3] = {-1e30f, -1e30f, -1e30f};
    for (int i = blockIdx.x * blockDim.x + tid; i < n; i += gridDim.x * blockDim.x) {
        #pragma unroll
        for (int c = 0; c < 3; ++c) {
            float v = pts[i * 3 + c];
            s[c] += v; mn[c] = fminf(mn[c], v); mx[c] = fmaxf(mx[c], v);
        }
    }
    for (int q = 0; q < 9; ++q) {
        float v = (q < 3) ? s[q] : (q < 6) ? mn[q - 3] : mx[q - 6];
        sm[tid] = v;
        __syncthreads();
        for (int o = 128; o > 0; o >>= 1) {
            if (tid < o) {
                float a = sm[tid], c = sm[tid + o];
                sm[tid] = (q < 3) ? a + c : (q < 6) ? fminf(a, c) : fmaxf(a, c);
            }
            __syncthreads();
        }
        if (tid == 0) partial[blockIdx.x * 9 + q] = sm[0];
        __syncthreads();
    }
}

__global__ __launch_bounds__(256) void pstat_final(
    const float* __restrict__ partial, float* __restrict__ stats, int n)
{
    __shared__ float sm[256];
    const int tid = threadIdx.x;
    for (int q = 0; q < 9; ++q) {
        float v = partial[tid * 9 + q];
        sm[tid] = v;
        __syncthreads();
        for (int o = 128; o > 0; o >>= 1) {
            if (tid < o) {
                float a = sm[tid], c = sm[tid + o];
                sm[tid] = (q < 3) ? a + c : (q < 6) ? fminf(a, c) : fmaxf(a, c);
            }
            __syncthreads();
        }
        if (tid == 0) sm[q] = sm[0];
        __syncthreads();
    }
    if (tid < 3) {
        float mean = sm[tid] / (float)n;
        float scale = fmaxf(fmaxf(sm[6 + tid] - mean, mean - sm[3 + tid]), 1e-6f);
        stats[tid] = mean;
        stats[3 + tid] = scale;
    }
}

// ---------------------------------------------------------------------------
// Gather kernel: one wave per point, zero LDS, high occupancy.
// Computes mean_feat (bf16 -> mf), boundary score (f32 -> bd).
// All K loads unconditional (safe index) + multiply-by-valid => 16 loads in
// flight per wave, no divergent branches in the hot loop.
// ---------------------------------------------------------------------------
__global__ __launch_bounds__(256) void gather_kernel(
    const unsigned* __restrict__ xb, const float* __restrict__ points,
    const int* __restrict__ neighbors,
    const float* __restrict__ bd_w1, const float* __restrict__ bd_b1,
    const float* __restrict__ bd_w2, const float* __restrict__ bd_b2,
    unsigned* __restrict__ mf, float* __restrict__ bd, int n)
{
    const int lane = threadIdx.x & 63;
    const int w    = threadIdx.x >> 6;
    const int i    = blockIdx.x * 4 + w;
    if (i >= n) return;

    // neighbor indices: lanes 0..15
    int nbr = 0, valid = 0;
    if (lane < K) {
        int v = neighbors[i * K + lane];
        valid = (v >= 0 && v < n) ? 1 : 0;
        nbr = valid ? v : 0;
    }
    const unsigned long long vm = __ballot(valid);          // bits 0..15
    const float denom = fmaxf((float)__popcll(vm), 1.0f);

    // gather neighbor feature rows (predicated, fully unrolled)
    float fx = 0.0f, fy = 0.0f;
    #pragma unroll
    for (int k = 0; k < K; ++k) {
        int nbk = __shfl(nbr, k, 64);
        float vf = ((vm >> k) & 1ull) ? 1.0f : 0.0f;        // wave-uniform
        unsigned v = xb[(size_t)nbk * (C / 2) + lane];
        fx += vf * bflo(v);
        fy += vf * bfhi(v);
    }
    const float mfx = fx / denom, mfy = fy / denom;
    unsigned pk = (unsigned short)f2bf(mfx) | ((unsigned)(unsigned short)f2bf(mfy) << 16);
    mf[(size_t)i * (C / 2) + lane] = pk;

    // feat_diff
    unsigned xv = xb[(size_t)i * (C / 2) + lane];
    float dx = bflo(xv) - mfx, dy = bfhi(xv) - mfy;
    float ss = dx * dx + dy * dy;
    #pragma unroll
    for (int o = 32; o > 0; o >>= 1) ss += __shfl_xor(ss, o, 64);
    const float fd = sqrtf(ss);

    // mean_point: lanes 0..15 load their neighbor's coords (predicated)
    float px = 0.0f, py = 0.0f, pz = 0.0f;
    if (lane < K) {
        float vf = valid ? 1.0f : 0.0f;
        px = vf * points[nbr * 3 + 0];
        py = vf * points[nbr * 3 + 1];
        pz = vf * points[nbr * 3 + 2];
    }
    #pragma unroll
    for (int o = 8; o > 0; o >>= 1) {
        px += __shfl_xor(px, o, 64);
        py += __shfl_xor(py, o, 64);
        pz += __shfl_xor(pz, o, 64);
    }
    const float mpx = __shfl(px, 0, 64) / denom;
    const float mpy = __shfl(py, 0, 64) / denom;
    const float mpz = __shfl(pz, 0, 64) / denom;
    const float c0 = points[i * 3 + 0] - mpx;
    const float c1 = points[i * 3 + 1] - mpy;
    const float c2 = points[i * 3 + 2] - mpz;
    const float cd = sqrtf(c0 * c0 + c1 * c1 + c2 * c2);

    // boundary MLP: 2 hidden units per lane
    float s = gelu_exact(fd * bd_w1[lane] + cd * bd_w1[H + lane] + bd_b1[lane]) * bd_w2[lane]
            + gelu_exact(fd * bd_w1[64 + lane] + cd * bd_w1[H + 64 + lane] + bd_b1[64 + lane]) * bd_w2[64 + lane];
    #pragma unroll
    for (int o = 32; o > 0; o >>= 1) s += __shfl_xor(s, o, 64);
    if (lane == 0) bd[i] = sigm(s + bd_b2[0]);
}

// ---------------------------------------------------------------------------
// MFMA GEMM helper for LDS-resident activations (hidden layers, K=128).
// ---------------------------------------------------------------------------
__device__ __forceinline__ void gemm_lds(const short* hrow, const short* __restrict__ wtg,
                                         int lane, int h4, f32x4 acc[8])
{
    #pragma unroll
    for (int c = 0; c < 4; ++c) {
        short8 af = *(const short8*)(hrow + c * 32 + h4 * 8);
        const short* wc = wtg + c * 4096 + lane * 8;
        #pragma unroll
        for (int t = 0; t < 8; ++t) {
            short8 wf = *(const short8*)(wc + t * 512);
            acc[t] = __builtin_amdgcn_mfma_f32_16x16x32_bf16(wf, af, acc[t], 0, 0, 0);
        }
    }
}

// ---------------------------------------------------------------------------
// Main fused kernel: 4 fully independent waves per block, 16 points/wave.
// x / mean_feat B-fragments read directly from global (L2-resident);
// only the dynamic 128-col hidden buffer lives in LDS. NO barriers.
// ---------------------------------------------------------------------------
__global__ __launch_bounds__(256, 3) void main_kernel(
    const unsigned* __restrict__ xb, const unsigned* __restrict__ mf,
    const float* __restrict__ bd, const float* __restrict__ feats,
    const float* __restrict__ points, const float* __restrict__ stats,
    const short* __restrict__ wt,
    const float* __restrict__ cp_w1, const float* __restrict__ cp_b1,
    const float* __restrict__ cp_b2,
    const float* __restrict__ mix_w1, const float* __restrict__ mix_b1,
    const float* __restrict__ mix_b2,
    const float* __restrict__ gate_w1, const float* __restrict__ gate_b1,
    const float* __restrict__ gate_b2,
    const float* __restrict__ out_b,
    float* __restrict__ out, int n)
{
    __shared__ __align__(16) short hid_s[PB * HS];   // 17408 B

    const int tid  = threadIdx.x;
    const int lane = tid & 63;
    const int w    = tid >> 6;
    const int m16  = lane & 15;
    const int h4   = lane >> 4;
    const int prow = w * 16 + m16;
    const int i0   = blockIdx.x * PB;
    const int ig   = i0 + prow;
    const int ip   = (ig < n) ? ig : (n - 1);        // clamped safe row

    const unsigned* __restrict__ xrow = xb + (size_t)ip * (C / 2);
    const unsigned* __restrict__ mrow = mf + (size_t)ip * (C / 2);
    short* hrow = hid_s + prow * HS;

    // per-point scalars
    const float px = (points[ip * 3 + 0] - stats[0]) / stats[3];
    const float py = (points[ip * 3 + 1] - stats[1]) / stats[4];
    const float pz = (points[ip * 3 + 2] - stats[2]) / stats[5];
    const float bdp = bd[ip];

    // ---- cp MLP: hidden in regs (B-fragment direct), cp2 GEMM -> ce in LDS ----
    {
        f32x4 acc[8];
        #pragma unroll
        for (int t = 0; t < 8; ++t) acc[t] = (f32x4)0.0f;
        #pragma unroll
        for (int c = 0; c < 4; ++c) {
            short8 af;
            #pragma unroll
            for (int j = 0; j < 8; ++j) {
                int hh = c * 32 + h4 * 8 + j;
                float hv = cp_b1[hh] + px * cp_w1[hh] + py * cp_w1[H + hh] + pz * cp_w1[2 * H + hh];
                af[j] = f2bf(gelu_exact(hv));
            }
            const short* wc = wt + WT_CP2 + c * 4096 + lane * 8;
            #pragma unroll
            for (int t = 0; t < 8; ++t) {
                short8 wf = *(const short8*)(wc + t * 512);
                acc[t] = __builtin_amdgcn_mfma_f32_16x16x32_bf16(wf, af, acc[t], 0, 0, 0);
            }
        }
        #pragma unroll
        for (int t = 0; t < 8; ++t) {
            f32x4 b = *(const f32x4*)(cp_b2 + t * 16 + h4 * 4);
            f32x4 v = acc[t] + b;
            short4v pk;
            #pragma unroll
            for (int r = 0; r < 4; ++r) pk[r] = f2bf(v[r]);
            *(short4v*)(hrow + t * 16 + h4 * 4) = pk;
        }
    }

    // ---- mix1 (K=384: x | mf | ce) + rank-1 boundary + bias, GELU -> hidden ----
    {
        f32x4 macc[8];
        #pragma unroll
        for (int t = 0; t < 8; ++t) macc[t] = (f32x4)0.0f;
        #pragma unroll
        for (int c = 0; c < 12; ++c) {
            short8 af;
            if (c < 4)      af = *(const short8*)(xrow + c * 16 + h4 * 4);
            else if (c < 8) af = *(const short8*)(mrow + (c - 4) * 16 + h4 * 4);
            else            af = *(const short8*)(hrow + (c - 8) * 32 + h4 * 8);
            const short* wc = wt + WT_MIX + c * 4096 + lane * 8;
            #pragma unroll
            for (int t = 0; t < 8; ++t) {
                short8 wf = *(const short8*)(wc + t * 512);
                macc[t] = __builtin_amdgcn_mfma_f32_16x16x32_bf16(wf, af, macc[t], 0, 0, 0);
            }
        }
        #pragma unroll
        for (int t = 0; t < 8; ++t) {
            f32x4 wb = *(const f32x4*)(mix_w1 + 256 * C + t * 16 + h4 * 4);
            f32x4 bb = *(const f32x4*)(mix_b1 + t * 16 + h4 * 4);
            f32x4 v = macc[t] + bdp * wb + bb;
            short4v pk;
            #pragma unroll
            for (int r = 0; r < 4; ++r) pk[r] = f2bf(gelu_exact(v[r]));
            *(short4v*)(hrow + t * 16 + h4 * 4) = pk;
        }
    }

    // ---- mix2 -> refined (regs) ----
    f32x4 refined[8];
    {
        #pragma unroll
        for (int t = 0; t < 8; ++t) refined[t] = (f32x4)0.0f;
        gemm_lds(hrow, wt + WT_MIX2, lane, h4, refined);
        #pragma unroll
        for (int t = 0; t < 8; ++t)
            refined[t] += *(const f32x4*)(mix_b2 + t * 16 + h4 * 4);
    }

    // ---- gate1 (K=256: x | mf) + rank-1 + bias, GELU -> hidden (overwrite) ----
    {
        f32x4 gacc[8];
        #pragma unroll
        for (int t = 0; t < 8; ++t) gacc[t] = (f32x4)0.0f;
        #pragma unroll
        for (int c = 0; c < 8; ++c) {
            short8 af;
            if (c < 4) af = *(const short8*)(xrow + c * 16 + h4 * 4);
            else       af = *(const short8*)(mrow + (c - 4) * 16 + h4 * 4);
            const short* wc = wt + WT_GATE + c * 4096 + lane * 8;
            #pragma unroll
            for (int t = 0; t < 8; ++t) {
                short8 wf = *(const short8*)(wc + t * 512);
                gacc[t] = __builtin_amdgcn_mfma_f32_16x16x32_bf16(wf, af, gacc[t], 0, 0, 0);
            }
        }
        #pragma unroll
        for (int t = 0; t < 8; ++t) {
            f32x4 wb = *(const f32x4*)(gate_w1 + 256 * C + t * 16 + h4 * 4);
            f32x4 bb = *(const f32x4*)(gate_b1 + t * 16 + h4 * 4);
            f32x4 v = gacc[t] + bdp * wb + bb;
            short4v pk;
            #pragma unroll
            for (int r = 0; r < 4; ++r) pk[r] = f2bf(gelu_exact(v[r]));
            *(short4v*)(hrow + t * 16 + h4 * 4) = pk;
        }
    }

    // ---- gate2 -> sigmoid * refined -> gr (overwrite hidden) ----
    {
        f32x4 gacc[8];
        #pragma unroll
        for (int t = 0; t < 8; ++t) gacc[t] = (f32x4)0.0f;
        gemm_lds(hrow, wt + WT_GATE2, lane, h4, gacc);
        #pragma unroll
        for (int t = 0; t < 8; ++t) {
            f32x4 bb = *(const f32x4*)(gate_b2 + t * 16 + h4 * 4);
            short4v pk;
            #pragma unroll
            for (int r = 0; r < 4; ++r)
                pk[r] = f2bf(sigm(gacc[t][r] + bb[r]) * refined[t][r]);
            *(short4v*)(hrow + t * 16 + h4 * 4) = pk;
        }
    }

    // ---- out GEMM + bias + residual -> direct global store ----
    {
        f32x4 oacc[8];
        #pragma unroll
        for (int t = 0; t < 8; ++t) oacc[t] = (f32x4)0.0f;
        gemm_lds(hrow, wt + WT_OUT, lane, h4, oacc);
        #pragma unroll
        for (int t = 0; t < 8; ++t) {
            int col = t * 16 + h4 * 4;
            f32x4 bb = *(const f32x4*)(out_b + col);
            f32x4 fv = *(const f32x4*)(feats + (size_t)ip * C + col);
            f32x4 v = oacc[t] + bb + fv;
            if (ig < n) *(f32x4*)(out + (size_t)ig * C + col) = v;
        }
    }
}

// ---------------------------------------------------------------------------
extern "C" void kernel_launch(void* const* d_in, const int* in_sizes, int n_in,
                              void* d_out, int out_size, void* d_ws, size_t ws_size,
                              hipStream_t stream)
{
    const float* feats     = (const float*)d_in[0];
    const float* points    = (const float*)d_in[1];
    const int*   neighbors = (const int*)d_in[2];
    const float* ln_g      = (const float*)d_in[3];
    const float* ln_b      = (const float*)d_in[4];
    const float* cp_w1     = (const float*)d_in[5];
    const float* cp_b1     = (const float*)d_in[6];
    const float* cp_w2     = (const float*)d_in[7];
    const float* cp_b2     = (const float*)d_in[8];
    const float* bd_w1     = (const float*)d_in[9];
    const float* bd_b1     = (const float*)d_in[10];
    const float* bd_w2     = (const float*)d_in[11];
    const float* bd_b2     = (const float*)d_in[12];
    const float* mix_w1    = (const float*)d_in[13];
    const float* mix_b1    = (const float*)d_in[14];
    const float* mix_w2    = (const float*)d_in[15];
    const float* mix_b2    = (const float*)d_in[16];
    const float* gate_w1   = (const float*)d_in[17];
    const float* gate_b1   = (const float*)d_in[18];
    const float* gate_w2   = (const float*)d_in[19];
    const float* gate_b2   = (const float*)d_in[20];
    const float* out_w     = (const float*)d_in[21];
    const float* out_b     = (const float*)d_in[22];
    float* out = (float*)d_out;
    (void)n_in; (void)out_size; (void)ws_size;

    const int n = in_sizes[0] / C;

    // ws layout: xb u32[N*64] | mf u32[N*64] | bd f32[N] | wt bf16[WT_TOTAL]
    //            | partial f32[NB2*9] | stats f32[6]
    char* base = (char*)d_ws;
    unsigned* xb   = (unsigned*)base;
    unsigned* mfp  = (unsigned*)(base + (size_t)n * C * 2);
    float* bdp     = (float*)(base + (size_t)n * C * 4);
    short* wt      = (short*)(base + (size_t)n * C * 4 + (size_t)n * 4);
    float* partial = (float*)((char*)wt + WT_TOTAL * 2);
    float* stats   = partial + NB2 * 9;

    prep_wt<<<36, 256, 0, stream>>>(mix_w1, gate_w1, cp_w2, mix_w2, gate_w2, out_w, wt);
    ln_kernel<<<(n + 3) / 4, 256, 0, stream>>>(feats, ln_g, ln_b, xb, n);
    pstat_partial<<<NB2, 256, 0, stream>>>(points, partial, n);
    pstat_final<<<1, 256, 0, stream>>>(partial, stats, n);
    gather_kernel<<<(n + 3) / 4, 256, 0, stream>>>(
        xb, points, neighbors, bd_w1, bd_b1, bd_w2, bd_b2, mfp, bdp, n);
    main_kernel<<<(n + PB - 1) / PB, 256, 0, stream>>>(
        xb, mfp, bdp, feats, points, stats, wt,
        cp_w1, cp_b1, cp_b2, mix_w1, mix_b1, mix_b2,
        gate_w1, gate_b1, gate_b2, out_b, out, n);
}

// Round 4
// 375.138 us; speedup vs baseline: 2.9385x; 1.0641x over previous
//
#include <hip/hip_runtime.h>
#include <math.h>

// Problem constants
constexpr int C    = 128;
constexpr int K    = 16;
constexpr int H    = 128;
constexpr int NB2  = 256;   // blocks for point-stat partial reduction
constexpr int WPTS = 32;    // points per wave
constexpr int PB   = 128;   // points per block (4 waves)
constexpr int HSU  = 68;    // activation row stride in u32 (136 bf16)

// Packed-weight offsets (bf16 elems) in ws: fragment order
constexpr int WT_MIX   = 0;        // K=384 -> 12 chunks
constexpr int WT_GATE  = 49152;    // K=256 -> 8 chunks
constexpr int WT_CP2   = 81920;    // K=128 -> 4 chunks
constexpr int WT_MIX2  = 98304;
constexpr int WT_GATE2 = 114688;
constexpr int WT_OUT   = 131072;
constexpr int WT_TOTAL = 147456;

typedef __attribute__((ext_vector_type(8))) short short8;
typedef __attribute__((ext_vector_type(4))) short short4v;
typedef __attribute__((ext_vector_type(4))) float f32x4;

__device__ __forceinline__ short f2bf(float f) {
    unsigned u = __float_as_uint(f);
    unsigned r = (u + 0x7fffu + ((u >> 16) & 1u)) >> 16;
    return (short)r;
}
__device__ __forceinline__ float bflo(unsigned v) { return __uint_as_float(v << 16); }
__device__ __forceinline__ float bfhi(unsigned v) { return __uint_as_float(v & 0xffff0000u); }
__device__ __forceinline__ float rcpf(float v) { return __builtin_amdgcn_rcpf(v); }

// A&S 7.1.26 erf-based exact-GELU (|erf err| < 1.5e-7)
__device__ __forceinline__ float gelu_f(float x) {
    float a = fabsf(x) * 0.70710678118654752440f;
    float t = rcpf(1.0f + 0.3275911f * a);
    float p = t * (0.254829592f + t * (-0.284496736f + t * (1.421413741f
            + t * (-1.453152027f + t * 1.061405429f))));
    float e = __expf(-a * a);
    float er = 1.0f - p * e;
    return 0.5f * x * (1.0f + copysignf(er, x));
}
__device__ __forceinline__ float sigm(float v) { return rcpf(1.0f + __expf(-v)); }

// ---------------------------------------------------------------------------
// Prep: pack weights to bf16 MFMA A-operand fragment order; block 36 writes
// the zero row (row n) of the xb table used for invalid neighbors.
// ---------------------------------------------------------------------------
__global__ __launch_bounds__(256) void prep_wt(
    const float* __restrict__ mix_w1, const float* __restrict__ gate_w1,
    const float* __restrict__ cp_w2,  const float* __restrict__ mix_w2,
    const float* __restrict__ gate_w2, const float* __restrict__ out_w,
    short* __restrict__ wt, unsigned* __restrict__ xb_zero_row)
{
    int b = blockIdx.x;
    if (b == 36) {
        if (threadIdx.x < 64) xb_zero_row[threadIdx.x] = 0u;
        return;
    }
    const float* src; int off; int c; bool skip256 = false;
    if (b < 12)      { src = mix_w1;  off = WT_MIX;   c = b;      skip256 = true; }
    else if (b < 20) { src = gate_w1; off = WT_GATE;  c = b - 12; }
    else if (b < 24) { src = cp_w2;   off = WT_CP2;   c = b - 20; }
    else if (b < 28) { src = mix_w2;  off = WT_MIX2;  c = b - 24; }
    else if (b < 32) { src = gate_w2; off = WT_GATE2; c = b - 28; }
    else             { src = out_w;   off = WT_OUT;   c = b - 32; }
    for (int ii = 0; ii < 16; ++ii) {
        int e = ii * 256 + threadIdx.x;   // 0..4095
        int j = e & 7, l = (e >> 3) & 63, t = e >> 9;
        int k = c * 32 + ((l >> 4) * 8) + j;
        int nn = t * 16 + (l & 15);
        int kk = (skip256 && k >= 256) ? k + 1 : k;
        wt[off + c * 4096 + e] = f2bf(src[kk * C + nn]);
    }
}

// ---------------------------------------------------------------------------
// LayerNorm -> packed bf16 x table (row stride 64 u32). One wave per point.
// ---------------------------------------------------------------------------
__global__ __launch_bounds__(256) void ln_kernel(
    const float* __restrict__ feats, const float* __restrict__ g,
    const float* __restrict__ b, unsigned* __restrict__ xb, int n)
{
    const int lane = threadIdx.x & 63;
    const int wave = threadIdx.x >> 6;
    const int i = blockIdx.x * 4 + wave;
    if (i >= n) return;
    const float2 f = *(const float2*)(feats + i * C + 2 * lane);
    float s = f.x + f.y;
    #pragma unroll
    for (int o = 32; o > 0; o >>= 1) s += __shfl_xor(s, o, 64);
    const float mu = s * (1.0f / C);
    const float d0 = f.x - mu, d1 = f.y - mu;
    float v = d0 * d0 + d1 * d1;
    #pragma unroll
    for (int o = 32; o > 0; o >>= 1) v += __shfl_xor(v, o, 64);
    const float rs = rsqrtf(v * (1.0f / C) + 1e-5f);
    const float x0 = d0 * rs * g[2 * lane] + b[2 * lane];
    const float x1 = d1 * rs * g[2 * lane + 1] + b[2 * lane + 1];
    unsigned pk = (unsigned short)f2bf(x0) | ((unsigned)(unsigned short)f2bf(x1) << 16);
    xb[(size_t)i * 64 + lane] = pk;
}

// ---------------------------------------------------------------------------
// Point stats
// ---------------------------------------------------------------------------
__global__ __launch_bounds__(256) void pstat_partial(
    const float* __restrict__ pts, float* __restrict__ partial, int n)
{
    __shared__ float sm[256];
    const int tid = threadIdx.x;
    float s[3] = {0, 0, 0};
    float mn[3] = {1e30f, 1e30f, 1e30f};
    float mx[3] = {-1e30f, -1e30f, -1e30f};
    for (int i = blockIdx.x * blockDim.x + tid; i < n; i += gridDim.x * blockDim.x) {
        #pragma unroll
        for (int c = 0; c < 3; ++c) {
            float v = pts[i * 3 + c];
            s[c] += v; mn[c] = fminf(mn[c], v); mx[c] = fmaxf(mx[c], v);
        }
    }
    for (int q = 0; q < 9; ++q) {
        float v = (q < 3) ? s[q] : (q < 6) ? mn[q - 3] : mx[q - 6];
        sm[tid] = v;
        __syncthreads();
        for (int o = 128; o > 0; o >>= 1) {
            if (tid < o) {
                float a = sm[tid], c = sm[tid + o];
                sm[tid] = (q < 3) ? a + c : (q < 6) ? fminf(a, c) : fmaxf(a, c);
            }
            __syncthreads();
        }
        if (tid == 0) partial[blockIdx.x * 9 + q] = sm[0];
        __syncthreads();
    }
}

__global__ __launch_bounds__(256) void pstat_final(
    const float* __restrict__ partial, float* __restrict__ stats, int n)
{
    __shared__ float sm[256];
    const int tid = threadIdx.x;
    for (int q = 0; q < 9; ++q) {
        float v = partial[tid * 9 + q];
        sm[tid] = v;
        __syncthreads();
        for (int o = 128; o > 0; o >>= 1) {
            if (tid < o) {
                float a = sm[tid], c = sm[tid + o];
                sm[tid] = (q < 3) ? a + c : (q < 6) ? fminf(a, c) : fmaxf(a, c);
            }
            __syncthreads();
        }
        if (tid == 0) sm[q] = sm[0];
        __syncthreads();
    }
    if (tid < 3) {
        float mean = sm[tid] / (float)n;
        float scale = fmaxf(fmaxf(sm[6 + tid] - mean, mean - sm[3 + tid]), 1e-6f);
        stats[tid] = mean;
        stats[3 + tid] = scale;
    }
}

// ---------------------------------------------------------------------------
// Fully fused main kernel: 4 independent waves/block, 32 points each.
// No __syncthreads anywhere — all buffers are wave-private row ranges.
// ---------------------------------------------------------------------------
__global__ __launch_bounds__(256, 2) void main_kernel(
    const unsigned* __restrict__ xb, const float* __restrict__ feats,
    const float* __restrict__ points, const int* __restrict__ neighbors,
    const float* __restrict__ stats, const short* __restrict__ wt,
    const float* __restrict__ cp_w1, const float* __restrict__ cp_b1,
    const float* __restrict__ cp_b2,
    const float* __restrict__ bd_w1, const float* __restrict__ bd_b1,
    const float* __restrict__ bd_w2, const float* __restrict__ bd_b2,
    const float* __restrict__ mix_w1, const float* __restrict__ mix_b1,
    const float* __restrict__ mix_b2,
    const float* __restrict__ gate_w1, const float* __restrict__ gate_b1,
    const float* __restrict__ gate_b2,
    const float* __restrict__ out_b,
    float* __restrict__ out, int n)
{
    // LDS: mf[128][68]u32 | hid[128][68]u32 | denom[128] | mp[128*3] | pts[128*4]
    //      | cd[128] | bd[128]   => 74,752 B  (2 blocks/CU)
    __shared__ __align__(16) char lds[74752];
    unsigned* mf_s  = (unsigned*)lds;
    unsigned* hid_s = (unsigned*)(lds + 34816);
    float* denom_s  = (float*)(lds + 69632);
    float* mp_s     = denom_s + 128;
    float* pts_s    = mp_s + 384;
    float* cd_s     = pts_s + 512;
    float* bd_s     = cd_s + 128;

    const int tid  = threadIdx.x;
    const int lane = tid & 63;
    const int w    = tid >> 6;
    const int m16  = lane & 15;
    const int h4   = lane >> 4;
    const int i0   = blockIdx.x * PB;
    const int wv32 = w * WPTS;
    const int i0w  = i0 + wv32;
    // per-wave neighbor scratch aliased into this wave's OWN hid rows
    // (written in phase A, read in gather, overwritten by ce afterwards)
    int* nb_w = (int*)(hid_s + (size_t)wv32 * HSU);

    // ================= Phase A: neighbor metadata =================
    {
        const int p0 = lane >> 2;               // 0..15
        const int jb = 4 * (lane & 3);
        const int r0 = min(i0w + p0, n - 1);
        const int r1 = min(i0w + 16 + p0, n - 1);
        const int4 A0 = *(const int4*)(neighbors + r0 * K + jb);
        const int4 A1 = *(const int4*)(neighbors + r1 * K + jb);

        const bool b00 = (unsigned)A0.x < (unsigned)n, b01 = (unsigned)A0.y < (unsigned)n;
        const bool b02 = (unsigned)A0.z < (unsigned)n, b03 = (unsigned)A0.w < (unsigned)n;
        const bool b10 = (unsigned)A1.x < (unsigned)n, b11 = (unsigned)A1.y < (unsigned)n;
        const bool b12 = (unsigned)A1.z < (unsigned)n, b13 = (unsigned)A1.w < (unsigned)n;

        // xb row index (invalid -> zero row n)
        *(int4*)&nb_w[4 * lane]       = make_int4(b00 ? A0.x : n, b01 ? A0.y : n,
                                                  b02 ? A0.z : n, b03 ? A0.w : n);
        *(int4*)&nb_w[256 + 4 * lane] = make_int4(b10 ? A1.x : n, b11 ? A1.y : n,
                                                  b12 ? A1.z : n, b13 ? A1.w : n);

        float c0 = (float)((int)b00 + (int)b01 + (int)b02 + (int)b03);
        float c1 = (float)((int)b10 + (int)b11 + (int)b12 + (int)b13);
        c0 += __shfl_xor(c0, 1, 64); c0 += __shfl_xor(c0, 2, 64);
        c1 += __shfl_xor(c1, 1, 64); c1 += __shfl_xor(c1, 2, 64);
        const float d0 = fmaxf(c0, 1.0f), d1 = fmaxf(c1, 1.0f);
        if ((lane & 3) == 0) {
            denom_s[wv32 + p0]      = d0;
            denom_s[wv32 + 16 + p0] = d1;
        }
        const float rd0 = rcpf(d0), rd1 = rcpf(d1);

        // mean_point: predicated coord sums, 4-lane group reduce
        const int q00 = b00 ? A0.x : 0, q01 = b01 ? A0.y : 0, q02 = b02 ? A0.z : 0, q03 = b03 ? A0.w : 0;
        const int q10 = b10 ? A1.x : 0, q11 = b11 ? A1.y : 0, q12 = b12 ? A1.z : 0, q13 = b13 ? A1.w : 0;
        const float f00 = b00 ? 1.f : 0.f, f01 = b01 ? 1.f : 0.f, f02 = b02 ? 1.f : 0.f, f03 = b03 ? 1.f : 0.f;
        const float f10 = b10 ? 1.f : 0.f, f11 = b11 ? 1.f : 0.f, f12 = b12 ? 1.f : 0.f, f13 = b13 ? 1.f : 0.f;
        #pragma unroll
        for (int c = 0; c < 3; ++c) {
            float s0 = f00 * points[q00 * 3 + c] + f01 * points[q01 * 3 + c]
                     + f02 * points[q02 * 3 + c] + f03 * points[q03 * 3 + c];
            float s1 = f10 * points[q10 * 3 + c] + f11 * points[q11 * 3 + c]
                     + f12 * points[q12 * 3 + c] + f13 * points[q13 * 3 + c];
            s0 += __shfl_xor(s0, 1, 64); s0 += __shfl_xor(s0, 2, 64);
            s1 += __shfl_xor(s1, 1, 64); s1 += __shfl_xor(s1, 2, 64);
            if ((lane & 3) == 0) {
                mp_s[(wv32 + p0) * 3 + c]      = s0 * rd0;
                mp_s[(wv32 + 16 + p0) * 3 + c] = s1 * rd1;
            }
        }
    }

    // own-point coords: coord_diff + normalized coords (lanes 0..31)
    if (lane < WPTS) {
        const int ipp = min(i0w + lane, n - 1);
        const float pv0 = points[ipp * 3 + 0];
        const float pv1 = points[ipp * 3 + 1];
        const float pv2 = points[ipp * 3 + 2];
        const float e0 = pv0 - mp_s[(wv32 + lane) * 3 + 0];
        const float e1 = pv1 - mp_s[(wv32 + lane) * 3 + 1];
        const float e2 = pv2 - mp_s[(wv32 + lane) * 3 + 2];
        cd_s[wv32 + lane] = sqrtf(e0 * e0 + e1 * e1 + e2 * e2);
        pts_s[(wv32 + lane) * 4 + 0] = (pv0 - stats[0]) * rcpf(stats[3]);
        pts_s[(wv32 + lane) * 4 + 1] = (pv1 - stats[1]) * rcpf(stats[4]);
        pts_s[(wv32 + lane) * 4 + 2] = (pv2 - stats[2]) * rcpf(stats[5]);
    }

    // boundary-MLP weights (2 hidden units per lane)
    const float bw_fa = bd_w1[lane],     bw_fb = bd_w1[64 + lane];
    const float bw_ca = bd_w1[H + lane], bw_cb = bd_w1[H + 64 + lane];
    const float bb1a  = bd_b1[lane],     bb1b  = bd_b1[64 + lane];
    const float bw2a  = bd_w2[lane],     bw2b  = bd_w2[64 + lane];
    const float bb2   = bd_b2[0];

    // ================= Phase B: gather + feat_diff + boundary =================
    for (int p = 0; p < WPTS; ++p) {
        const int* nbp = nb_w + p * K;
        float fx = 0.0f, fy = 0.0f;
        #pragma unroll
        for (int k = 0; k < K; ++k) {
            const int idx = nbp[k];                        // uniform broadcast
            const unsigned v = xb[(size_t)idx * 64 + lane];
            fx += bflo(v); fy += bfhi(v);
        }
        const float rden = rcpf(denom_s[wv32 + p]);
        const float mfx = fx * rden, mfy = fy * rden;
        mf_s[(wv32 + p) * HSU + lane] =
            (unsigned)(unsigned short)f2bf(mfx) | ((unsigned)(unsigned short)f2bf(mfy) << 16);
        const int ipp = min(i0w + p, n - 1);
        const unsigned xv = xb[(size_t)ipp * 64 + lane];
        const float dx = bflo(xv) - mfx, dy = bfhi(xv) - mfy;
        float ss = dx * dx + dy * dy;
        #pragma unroll
        for (int o = 32; o > 0; o >>= 1) ss += __shfl_xor(ss, o, 64);
        const float fd = sqrtf(ss);
        const float cd = cd_s[wv32 + p];
        float s = gelu_f(fd * bw_fa + cd * bw_ca + bb1a) * bw2a
                + gelu_f(fd * bw_fb + cd * bw_cb + bb1b) * bw2b;
        #pragma unroll
        for (int o = 32; o > 0; o >>= 1) s += __shfl_xor(s, o, 64);
        if (lane == 0) bd_s[wv32 + p] = sigm(s + bb2);
    }

    // ================= GEMM phases (2 groups of 16 points per wave) ==========
    const int pr0 = wv32 + m16, pr1 = wv32 + 16 + m16;
    const int ig0 = i0 + pr0,   ig1 = i0 + pr1;
    const int ip0 = min(ig0, n - 1), ip1 = min(ig1, n - 1);
    const unsigned* xr0  = xb + (size_t)ip0 * 64;
    const unsigned* xr1  = xb + (size_t)ip1 * 64;
    const unsigned* mfr0 = mf_s + pr0 * HSU;
    const unsigned* mfr1 = mf_s + pr1 * HSU;
    unsigned* hr0 = hid_s + pr0 * HSU;
    unsigned* hr1 = hid_s + pr1 * HSU;

    // ---- cp MLP: hidden from regs, cp2 GEMM -> ce into hid ----
    {
        const float px0 = pts_s[pr0 * 4], py0 = pts_s[pr0 * 4 + 1], pz0 = pts_s[pr0 * 4 + 2];
        const float px1 = pts_s[pr1 * 4], py1 = pts_s[pr1 * 4 + 1], pz1 = pts_s[pr1 * 4 + 2];
        f32x4 a0[8], a1[8];
        #pragma unroll
        for (int t = 0; t < 8; ++t) { a0[t] = (f32x4)0.0f; a1[t] = (f32x4)0.0f; }
        #pragma unroll
        for (int c = 0; c < 4; ++c) {
            short8 af0, af1;
            #pragma unroll
            for (int j = 0; j < 8; ++j) {
                const int hh = c * 32 + h4 * 8 + j;
                const float wa = cp_w1[hh], wb = cp_w1[H + hh], wc2 = cp_w1[2 * H + hh];
                const float bb = cp_b1[hh];
                af0[j] = f2bf(gelu_f(bb + px0 * wa + py0 * wb + pz0 * wc2));
                af1[j] = f2bf(gelu_f(bb + px1 * wa + py1 * wb + pz1 * wc2));
            }
            const short* wcp = wt + WT_CP2 + c * 4096 + lane * 8;
            #pragma unroll
            for (int t = 0; t < 8; ++t) {
                const short8 wf = *(const short8*)(wcp + t * 512);
                a0[t] = __builtin_amdgcn_mfma_f32_16x16x32_bf16(wf, af0, a0[t], 0, 0, 0);
                a1[t] = __builtin_amdgcn_mfma_f32_16x16x32_bf16(wf, af1, a1[t], 0, 0, 0);
            }
        }
        #pragma unroll
        for (int t = 0; t < 8; ++t) {
            const f32x4 bb = *(const f32x4*)(cp_b2 + t * 16 + h4 * 4);
            const f32x4 v0 = a0[t] + bb, v1 = a1[t] + bb;
            short4v pk0, pk1;
            #pragma unroll
            for (int r = 0; r < 4; ++r) { pk0[r] = f2bf(v0[r]); pk1[r] = f2bf(v1[r]); }
            *(short4v*)((short*)hr0 + t * 16 + h4 * 4) = pk0;
            *(short4v*)((short*)hr1 + t * 16 + h4 * 4) = pk1;
        }
    }

    const float bdp0 = bd_s[pr0], bdp1 = bd_s[pr1];

    // ---- mix1 (K=384: x | mf | ce) + rank-1 + bias, GELU -> hid ----
    {
        f32x4 a0[8], a1[8];
        #pragma unroll
        for (int t = 0; t < 8; ++t) { a0[t] = (f32x4)0.0f; a1[t] = (f32x4)0.0f; }
        #pragma unroll
        for (int c = 0; c < 12; ++c) {
            short8 af0, af1;
            if (c < 4) {
                af0 = *(const short8*)(xr0 + c * 16 + h4 * 4);
                af1 = *(const short8*)(xr1 + c * 16 + h4 * 4);
            } else if (c < 8) {
                af0 = *(const short8*)(mfr0 + (c - 4) * 16 + h4 * 4);
                af1 = *(const short8*)(mfr1 + (c - 4) * 16 + h4 * 4);
            } else {
                af0 = *(const short8*)(hr0 + (c - 8) * 16 + h4 * 4);
                af1 = *(const short8*)(hr1 + (c - 8) * 16 + h4 * 4);
            }
            const short* wmc = wt + WT_MIX + c * 4096 + lane * 8;
            #pragma unroll
            for (int t = 0; t < 8; ++t) {
                const short8 wf = *(const short8*)(wmc + t * 512);
                a0[t] = __builtin_amdgcn_mfma_f32_16x16x32_bf16(wf, af0, a0[t], 0, 0, 0);
                a1[t] = __builtin_amdgcn_mfma_f32_16x16x32_bf16(wf, af1, a1[t], 0, 0, 0);
            }
        }
        #pragma unroll
        for (int t = 0; t < 8; ++t) {
            const int col = t * 16 + h4 * 4;
            const f32x4 wb = *(const f32x4*)(mix_w1 + 256 * C + col);
            const f32x4 bb = *(const f32x4*)(mix_b1 + col);
            const f32x4 v0 = a0[t] + bdp0 * wb + bb;
            const f32x4 v1 = a1[t] + bdp1 * wb + bb;
            short4v pk0, pk1;
            #pragma unroll
            for (int r = 0; r < 4; ++r) { pk0[r] = f2bf(gelu_f(v0[r])); pk1[r] = f2bf(gelu_f(v1[r])); }
            *(short4v*)((short*)hr0 + col) = pk0;
            *(short4v*)((short*)hr1 + col) = pk1;
        }
    }

    // ---- mix2 -> refined (regs) ----
    f32x4 rf0[8], rf1[8];
    {
        #pragma unroll
        for (int t = 0; t < 8; ++t) { rf0[t] = (f32x4)0.0f; rf1[t] = (f32x4)0.0f; }
        #pragma unroll
        for (int c = 0; c < 4; ++c) {
            const short8 af0 = *(const short8*)(hr0 + c * 16 + h4 * 4);
            const short8 af1 = *(const short8*)(hr1 + c * 16 + h4 * 4);
            const short* wmc = wt + WT_MIX2 + c * 4096 + lane * 8;
            #pragma unroll
            for (int t = 0; t < 8; ++t) {
                const short8 wf = *(const short8*)(wmc + t * 512);
                rf0[t] = __builtin_amdgcn_mfma_f32_16x16x32_bf16(wf, af0, rf0[t], 0, 0, 0);
                rf1[t] = __builtin_amdgcn_mfma_f32_16x16x32_bf16(wf, af1, rf1[t], 0, 0, 0);
            }
        }
        #pragma unroll
        for (int t = 0; t < 8; ++t) {
            const f32x4 bb = *(const f32x4*)(mix_b2 + t * 16 + h4 * 4);
            rf0[t] += bb; rf1[t] += bb;
        }
    }

    // ---- gate1 (K=256: x | mf) + rank-1 + bias, GELU -> hid (overwrite) ----
    {
        f32x4 a0[8], a1[8];
        #pragma unroll
        for (int t = 0; t < 8; ++t) { a0[t] = (f32x4)0.0f; a1[t] = (f32x4)0.0f; }
        #pragma unroll
        for (int c = 0; c < 8; ++c) {
            short8 af0, af1;
            if (c < 4) {
                af0 = *(const short8*)(xr0 + c * 16 + h4 * 4);
                af1 = *(const short8*)(xr1 + c * 16 + h4 * 4);
            } else {
                af0 = *(const short8*)(mfr0 + (c - 4) * 16 + h4 * 4);
                af1 = *(const short8*)(mfr1 + (c - 4) * 16 + h4 * 4);
            }
            const short* wgc = wt + WT_GATE + c * 4096 + lane * 8;
            #pragma unroll
            for (int t = 0; t < 8; ++t) {
                const short8 wf = *(const short8*)(wgc + t * 512);
                a0[t] = __builtin_amdgcn_mfma_f32_16x16x32_bf16(wf, af0, a0[t], 0, 0, 0);
                a1[t] = __builtin_amdgcn_mfma_f32_16x16x32_bf16(wf, af1, a1[t], 0, 0, 0);
            }
        }
        #pragma unroll
        for (int t = 0; t < 8; ++t) {
            const int col = t * 16 + h4 * 4;
            const f32x4 wb = *(const f32x4*)(gate_w1 + 256 * C + col);
            const f32x4 bb = *(const f32x4*)(gate_b1 + col);
            const f32x4 v0 = a0[t] + bdp0 * wb + bb;
            const f32x4 v1 = a1[t] + bdp1 * wb + bb;
            short4v pk0, pk1;
            #pragma unroll
            for (int r = 0; r < 4; ++r) { pk0[r] = f2bf(gelu_f(v0[r])); pk1[r] = f2bf(gelu_f(v1[r])); }
            *(short4v*)((short*)hr0 + col) = pk0;
            *(short4v*)((short*)hr1 + col) = pk1;
        }
    }

    // ---- gate2 -> sigmoid * refined -> gr (overwrite hid) ----
    {
        f32x4 a0[8], a1[8];
        #pragma unroll
        for (int t = 0; t < 8; ++t) { a0[t] = (f32x4)0.0f; a1[t] = (f32x4)0.0f; }
        #pragma unroll
        for (int c = 0; c < 4; ++c) {
            const short8 af0 = *(const short8*)(hr0 + c * 16 + h4 * 4);
            const short8 af1 = *(const short8*)(hr1 + c * 16 + h4 * 4);
            const short* wgc = wt + WT_GATE2 + c * 4096 + lane * 8;
            #pragma unroll
            for (int t = 0; t < 8; ++t) {
                const short8 wf = *(const short8*)(wgc + t * 512);
                a0[t] = __builtin_amdgcn_mfma_f32_16x16x32_bf16(wf, af0, a0[t], 0, 0, 0);
                a1[t] = __builtin_amdgcn_mfma_f32_16x16x32_bf16(wf, af1, a1[t], 0, 0, 0);
            }
        }
        #pragma unroll
        for (int t = 0; t < 8; ++t) {
            const int col = t * 16 + h4 * 4;
            const f32x4 bb = *(const f32x4*)(gate_b2 + col);
            short4v pk0, pk1;
            #pragma unroll
            for (int r = 0; r < 4; ++r) {
                pk0[r] = f2bf(sigm(a0[t][r] + bb[r]) * rf0[t][r]);
                pk1[r] = f2bf(sigm(a1[t][r] + bb[r]) * rf1[t][r]);
            }
            *(short4v*)((short*)hr0 + col) = pk0;
            *(short4v*)((short*)hr1 + col) = pk1;
        }
    }

    // ---- out GEMM + bias + residual -> global store ----
    {
        f32x4 a0[8], a1[8];
        #pragma unroll
        for (int t = 0; t < 8; ++t) { a0[t] = (f32x4)0.0f; a1[t] = (f32x4)0.0f; }
        #pragma unroll
        for (int c = 0; c < 4; ++c) {
            const short8 af0 = *(const short8*)(hr0 + c * 16 + h4 * 4);
            const short8 af1 = *(const short8*)(hr1 + c * 16 + h4 * 4);
            const short* woc = wt + WT_OUT + c * 4096 + lane * 8;
            #pragma unroll
            for (int t = 0; t < 8; ++t) {
                const short8 wf = *(const short8*)(woc + t * 512);
                a0[t] = __builtin_amdgcn_mfma_f32_16x16x32_bf16(wf, af0, a0[t], 0, 0, 0);
                a1[t] = __builtin_amdgcn_mfma_f32_16x16x32_bf16(wf, af1, a1[t], 0, 0, 0);
            }
        }
        #pragma unroll
        for (int t = 0; t < 8; ++t) {
            const int col = t * 16 + h4 * 4;
            const f32x4 bb = *(const f32x4*)(out_b + col);
            const f32x4 fv0 = *(const f32x4*)(feats + (size_t)ip0 * C + col);
            const f32x4 fv1 = *(const f32x4*)(feats + (size_t)ip1 * C + col);
            const f32x4 v0 = a0[t] + bb + fv0;
            const f32x4 v1 = a1[t] + bb + fv1;
            if (ig0 < n) *(f32x4*)(out + (size_t)ig0 * C + col) = v0;
            if (ig1 < n) *(f32x4*)(out + (size_t)ig1 * C + col) = v1;
        }
    }
}

// ---------------------------------------------------------------------------
extern "C" void kernel_launch(void* const* d_in, const int* in_sizes, int n_in,
                              void* d_out, int out_size, void* d_ws, size_t ws_size,
                              hipStream_t stream)
{
    const float* feats     = (const float*)d_in[0];
    const float* points    = (const float*)d_in[1];
    const int*   neighbors = (const int*)d_in[2];
    const float* ln_g      = (const float*)d_in[3];
    const float* ln_b      = (const float*)d_in[4];
    const float* cp_w1     = (const float*)d_in[5];
    const float* cp_b1     = (const float*)d_in[6];
    const float* cp_w2     = (const float*)d_in[7];
    const float* cp_b2     = (const float*)d_in[8];
    const float* bd_w1     = (const float*)d_in[9];
    const float* bd_b1     = (const float*)d_in[10];
    const float* bd_w2     = (const float*)d_in[11];
    const float* bd_b2     = (const float*)d_in[12];
    const float* mix_w1    = (const float*)d_in[13];
    const float* mix_b1    = (const float*)d_in[14];
    const float* mix_w2    = (const float*)d_in[15];
    const float* mix_b2    = (const float*)d_in[16];
    const float* gate_w1   = (const float*)d_in[17];
    const float* gate_b1   = (const float*)d_in[18];
    const float* gate_w2   = (const float*)d_in[19];
    const float* gate_b2   = (const float*)d_in[20];
    const float* out_w     = (const float*)d_in[21];
    const float* out_b     = (const float*)d_in[22];
    float* out = (float*)d_out;
    (void)n_in; (void)out_size; (void)ws_size;

    const int n = in_sizes[0] / C;

    // ws layout: xb u32[(n+1)*64] | wt bf16[WT_TOTAL] | partial f32[NB2*9] | stats f32[6]
    char* base = (char*)d_ws;
    unsigned* xb   = (unsigned*)base;
    short* wt      = (short*)(base + (size_t)(n + 1) * 256);
    float* partial = (float*)((char*)wt + (size_t)WT_TOTAL * 2);
    float* stats   = partial + NB2 * 9;

    prep_wt<<<37, 256, 0, stream>>>(mix_w1, gate_w1, cp_w2, mix_w2, gate_w2, out_w,
                                    wt, xb + (size_t)n * 64);
    ln_kernel<<<(n + 3) / 4, 256, 0, stream>>>(feats, ln_g, ln_b, xb, n);
    pstat_partial<<<NB2, 256, 0, stream>>>(points, partial, n);
    pstat_final<<<1, 256, 0, stream>>>(partial, stats, n);
    main_kernel<<<(n + PB - 1) / PB, 256, 0, stream>>>(
        xb, feats, points, neighbors, stats, wt,
        cp_w1, cp_b1, cp_b2, bd_w1, bd_b1, bd_w2, bd_b2,
        mix_w1, mix_b1, mix_b2, gate_w1, gate_b1, gate_b2,
        out_b, out, n);
}

// Round 6
// 338.662 us; speedup vs baseline: 3.2550x; 1.1077x over previous
//
#include <hip/hip_runtime.h>
#include <math.h>

// Problem constants
constexpr int C    = 128;
constexpr int K    = 16;
constexpr int H    = 128;
constexpr int NB2  = 256;   // blocks for point-stat partial reduction
constexpr int WPTS = 32;    // points per wave
constexpr int PB   = 128;   // points per block (4 waves)
constexpr int HSU  = 68;    // activation row stride in u32 (136 bf16)

// Packed-weight offsets (bf16 elems) in ws: fragment order
constexpr int WT_MIX   = 0;        // K=384 -> 12 chunks
constexpr int WT_GATE  = 49152;    // K=256 -> 8 chunks
constexpr int WT_CP2   = 81920;    // K=128 -> 4 chunks
constexpr int WT_MIX2  = 98304;
constexpr int WT_GATE2 = 114688;
constexpr int WT_OUT   = 131072;
constexpr int WT_TOTAL = 147456;

typedef __attribute__((ext_vector_type(8))) short short8;
typedef __attribute__((ext_vector_type(4))) short short4v;
typedef __attribute__((ext_vector_type(4))) float f32x4;

__device__ __forceinline__ short f2bf(float f) {
    unsigned u = __float_as_uint(f);
    unsigned r = (u + 0x7fffu + ((u >> 16) & 1u)) >> 16;
    return (short)r;
}
__device__ __forceinline__ float bflo(unsigned v) { return __uint_as_float(v << 16); }
__device__ __forceinline__ float bfhi(unsigned v) { return __uint_as_float(v & 0xffff0000u); }
__device__ __forceinline__ float rcpf(float v) { return __builtin_amdgcn_rcpf(v); }

// e5m2 = truncated fp16: decode = byte<<8 reinterpret as _Float16
__device__ __forceinline__ float e5m2f(unsigned b) {
    union { unsigned short u; _Float16 h; } cv;
    cv.u = (unsigned short)((b & 0xFFu) << 8);
    return (float)cv.h;
}
__device__ __forceinline__ unsigned f2e5m2(float x) {
    union { _Float16 h; unsigned short u; } cv;
    cv.h = (_Float16)x;
    return ((unsigned)cv.u + 0x7Fu + ((cv.u >> 8) & 1u)) >> 8;
}

// A&S 7.1.26 erf-based exact-GELU (|erf err| < 1.5e-7)
__device__ __forceinline__ float gelu_f(float x) {
    float a = fabsf(x) * 0.70710678118654752440f;
    float t = rcpf(1.0f + 0.3275911f * a);
    float p = t * (0.254829592f + t * (-0.284496736f + t * (1.421413741f
            + t * (-1.453152027f + t * 1.061405429f))));
    float e = __expf(-a * a);
    float er = 1.0f - p * e;
    return 0.5f * x * (1.0f + copysignf(er, x));
}
__device__ __forceinline__ float sigm(float v) { return rcpf(1.0f + __expf(-v)); }

// ---------------------------------------------------------------------------
// Prep: blocks 0..35 pack weights; block 36 zero rows (xb, xg); blocks 37+
// build pts4 table (incl. zero row n).
// ---------------------------------------------------------------------------
__global__ __launch_bounds__(256) void prep_wt(
    const float* __restrict__ mix_w1, const float* __restrict__ gate_w1,
    const float* __restrict__ cp_w2,  const float* __restrict__ mix_w2,
    const float* __restrict__ gate_w2, const float* __restrict__ out_w,
    const float* __restrict__ points,
    short* __restrict__ wt, unsigned* __restrict__ xb_zero,
    unsigned* __restrict__ xg_zero, float* __restrict__ pts4, int n)
{
    int b = blockIdx.x;
    if (b == 36) {
        if (threadIdx.x < 64) xb_zero[threadIdx.x] = 0u;
        else if (threadIdx.x < 96) xg_zero[threadIdx.x - 64] = 0u;
        return;
    }
    if (b >= 37) {
        int i = (b - 37) * 256 + threadIdx.x;
        if (i < n) {
            pts4[i * 4 + 0] = points[i * 3 + 0];
            pts4[i * 4 + 1] = points[i * 3 + 1];
            pts4[i * 4 + 2] = points[i * 3 + 2];
            pts4[i * 4 + 3] = 0.0f;
        } else if (i == n) {
            pts4[i * 4 + 0] = 0.0f; pts4[i * 4 + 1] = 0.0f;
            pts4[i * 4 + 2] = 0.0f; pts4[i * 4 + 3] = 0.0f;
        }
        return;
    }
    const float* src; int off; int c; bool skip256 = false;
    if (b < 12)      { src = mix_w1;  off = WT_MIX;   c = b;      skip256 = true; }
    else if (b < 20) { src = gate_w1; off = WT_GATE;  c = b - 12; }
    else if (b < 24) { src = cp_w2;   off = WT_CP2;   c = b - 20; }
    else if (b < 28) { src = mix_w2;  off = WT_MIX2;  c = b - 24; }
    else if (b < 32) { src = gate_w2; off = WT_GATE2; c = b - 28; }
    else             { src = out_w;   off = WT_OUT;   c = b - 32; }
    for (int ii = 0; ii < 16; ++ii) {
        int e = ii * 256 + threadIdx.x;   // 0..4095
        int j = e & 7, l = (e >> 3) & 63, t = e >> 9;
        int k = c * 32 + ((l >> 4) * 8) + j;
        int nn = t * 16 + (l & 15);
        int kk = (skip256 && k >= 256) ? k + 1 : k;
        wt[off + c * 4096 + e] = f2bf(src[kk * C + nn]);
    }
}

// ---------------------------------------------------------------------------
// LayerNorm -> bf16 xb (256 B rows) + e5m2 xg (128 B rows). One wave/point.
// ---------------------------------------------------------------------------
__global__ __launch_bounds__(256) void ln_kernel(
    const float* __restrict__ feats, const float* __restrict__ g,
    const float* __restrict__ b, unsigned* __restrict__ xb,
    unsigned short* __restrict__ xg, int n)
{
    const int lane = threadIdx.x & 63;
    const int wave = threadIdx.x >> 6;
    const int i = blockIdx.x * 4 + wave;
    if (i >= n) return;
    const float2 f = *(const float2*)(feats + i * C + 2 * lane);
    float s = f.x + f.y;
    #pragma unroll
    for (int o = 32; o > 0; o >>= 1) s += __shfl_xor(s, o, 64);
    const float mu = s * (1.0f / C);
    const float d0 = f.x - mu, d1 = f.y - mu;
    float v = d0 * d0 + d1 * d1;
    #pragma unroll
    for (int o = 32; o > 0; o >>= 1) v += __shfl_xor(v, o, 64);
    const float rs = rsqrtf(v * (1.0f / C) + 1e-5f);
    const float x0 = d0 * rs * g[2 * lane] + b[2 * lane];
    const float x1 = d1 * rs * g[2 * lane + 1] + b[2 * lane + 1];
    xb[(size_t)i * 64 + lane] =
        (unsigned)(unsigned short)f2bf(x0) | ((unsigned)(unsigned short)f2bf(x1) << 16);
    xg[(size_t)i * 64 + lane] =
        (unsigned short)(f2e5m2(x0) | (f2e5m2(x1) << 8));
}

// ---------------------------------------------------------------------------
// Point stats
// ---------------------------------------------------------------------------
__global__ __launch_bounds__(256) void pstat_partial(
    const float* __restrict__ pts, float* __restrict__ partial, int n)
{
    __shared__ float sm[256];
    const int tid = threadIdx.x;
    float s[3] = {0, 0, 0};
    float mn[3] = {1e30f, 1e30f, 1e30f};
    float mx[3] = {-1e30f, -1e30f, -1e30f};
    for (int i = blockIdx.x * blockDim.x + tid; i < n; i += gridDim.x * blockDim.x) {
        #pragma unroll
        for (int c = 0; c < 3; ++c) {
            float v = pts[i * 3 + c];
            s[c] += v; mn[c] = fminf(mn[c], v); mx[c] = fmaxf(mx[c], v);
        }
    }
    for (int q = 0; q < 9; ++q) {
        float v = (q < 3) ? s[q] : (q < 6) ? mn[q - 3] : mx[q - 6];
        sm[tid] = v;
        __syncthreads();
        for (int o = 128; o > 0; o >>= 1) {
            if (tid < o) {
                float a = sm[tid], c = sm[tid + o];
                sm[tid] = (q < 3) ? a + c : (q < 6) ? fminf(a, c) : fmaxf(a, c);
            }
            __syncthreads();
        }
        if (tid == 0) partial[blockIdx.x * 9 + q] = sm[0];
        __syncthreads();
    }
}

__global__ __launch_bounds__(256) void pstat_final(
    const float* __restrict__ partial, float* __restrict__ stats, int n)
{
    __shared__ float sm[256];
    const int tid = threadIdx.x;
    for (int q = 0; q < 9; ++q) {
        float v = partial[tid * 9 + q];
        sm[tid] = v;
        __syncthreads();
        for (int o = 128; o > 0; o >>= 1) {
            if (tid < o) {
                float a = sm[tid], c = sm[tid + o];
                sm[tid] = (q < 3) ? a + c : (q < 6) ? fminf(a, c) : fmaxf(a, c);
            }
            __syncthreads();
        }
        if (tid == 0) sm[q] = sm[0];
        __syncthreads();
    }
    if (tid < 3) {
        float mean = sm[tid] / (float)n;
        float scale = fmaxf(fmaxf(sm[6 + tid] - mean, mean - sm[3 + tid]), 1e-6f);
        stats[tid] = mean;
        stats[3 + tid] = scale;
    }
}

// ---------------------------------------------------------------------------
// Fully fused main kernel: 4 independent waves/block, 32 points each.
// No __syncthreads — all buffers wave-private row ranges.
// ---------------------------------------------------------------------------
__global__ __launch_bounds__(256, 2) void main_kernel(
    const unsigned* __restrict__ xb, const unsigned* __restrict__ xg,
    const float* __restrict__ pts4, const float* __restrict__ feats,
    const int* __restrict__ neighbors,
    const float* __restrict__ stats, const short* __restrict__ wt,
    const float* __restrict__ cp_w1, const float* __restrict__ cp_b1,
    const float* __restrict__ cp_b2,
    const float* __restrict__ bd_w1, const float* __restrict__ bd_b1,
    const float* __restrict__ bd_w2, const float* __restrict__ bd_b2,
    const float* __restrict__ mix_w1, const float* __restrict__ mix_b1,
    const float* __restrict__ mix_b2,
    const float* __restrict__ gate_w1, const float* __restrict__ gate_b1,
    const float* __restrict__ gate_b2,
    const float* __restrict__ out_b,
    float* __restrict__ out, int n)
{
    // LDS: mf[128][68]u32 | hid[128][68]u32 | denom[128] | pts[128*4] | cd[128] | bd[128]
    __shared__ __align__(16) char lds[73216];
    unsigned* mf_s  = (unsigned*)lds;
    unsigned* hid_s = (unsigned*)(lds + 34816);
    float* denom_s  = (float*)(lds + 69632);
    float* pts_s    = denom_s + 128;
    float* cd_s     = pts_s + 512;
    float* bd_s     = cd_s + 128;

    const int tid  = threadIdx.x;
    const int lane = tid & 63;
    const int w    = tid >> 6;
    const int m16  = lane & 15;
    const int h4   = lane >> 4;
    const int i0   = blockIdx.x * PB;
    const int wv32 = w * WPTS;
    const int i0w  = i0 + wv32;
    // per-wave neighbor scratch aliased into this wave's OWN hid rows
    int* nb_w = (int*)(hid_s + (size_t)wv32 * HSU);

    // ================= Phase A: neighbor metadata =================
    {
        const int p0 = lane >> 2;               // 0..15
        const int jb = 4 * (lane & 3);
        const int r0 = min(i0w + p0, n - 1);
        const int r1 = min(i0w + 16 + p0, n - 1);
        const int4 A0 = *(const int4*)(neighbors + (size_t)r0 * K + jb);
        const int4 A1 = *(const int4*)(neighbors + (size_t)r1 * K + jb);

        const int q00 = ((unsigned)A0.x < (unsigned)n) ? A0.x : n;
        const int q01 = ((unsigned)A0.y < (unsigned)n) ? A0.y : n;
        const int q02 = ((unsigned)A0.z < (unsigned)n) ? A0.z : n;
        const int q03 = ((unsigned)A0.w < (unsigned)n) ? A0.w : n;
        const int q10 = ((unsigned)A1.x < (unsigned)n) ? A1.x : n;
        const int q11 = ((unsigned)A1.y < (unsigned)n) ? A1.y : n;
        const int q12 = ((unsigned)A1.z < (unsigned)n) ? A1.z : n;
        const int q13 = ((unsigned)A1.w < (unsigned)n) ? A1.w : n;

        *(int4*)&nb_w[4 * lane]       = make_int4(q00, q01, q02, q03);
        *(int4*)&nb_w[256 + 4 * lane] = make_int4(q10, q11, q12, q13);

        float c0 = (float)((q00 != n) + (q01 != n) + (q02 != n) + (q03 != n));
        float c1 = (float)((q10 != n) + (q11 != n) + (q12 != n) + (q13 != n));
        c0 += __shfl_xor(c0, 1, 64); c0 += __shfl_xor(c0, 2, 64);
        c1 += __shfl_xor(c1, 1, 64); c1 += __shfl_xor(c1, 2, 64);
        const float d0 = fmaxf(c0, 1.0f), d1 = fmaxf(c1, 1.0f);
        if ((lane & 3) == 0) {
            denom_s[wv32 + p0]      = d0;
            denom_s[wv32 + 16 + p0] = d1;
        }

        // mean_point via pts4 (zero row for invalid) + 4-lane reduce
        f32x4 s0 = *(const f32x4*)(pts4 + 4 * q00);
        s0 += *(const f32x4*)(pts4 + 4 * q01);
        s0 += *(const f32x4*)(pts4 + 4 * q02);
        s0 += *(const f32x4*)(pts4 + 4 * q03);
        f32x4 s1 = *(const f32x4*)(pts4 + 4 * q10);
        s1 += *(const f32x4*)(pts4 + 4 * q11);
        s1 += *(const f32x4*)(pts4 + 4 * q12);
        s1 += *(const f32x4*)(pts4 + 4 * q13);
        #pragma unroll
        for (int c = 0; c < 3; ++c) {
            s0[c] += __shfl_xor(s0[c], 1, 64); s0[c] += __shfl_xor(s0[c], 2, 64);
            s1[c] += __shfl_xor(s1[c], 1, 64); s1[c] += __shfl_xor(s1[c], 2, 64);
        }
        if ((lane & 3) == 0) {
            const float rd0 = rcpf(d0), rd1 = rcpf(d1);
            const f32x4 pv0 = *(const f32x4*)(pts4 + 4 * r0);
            const f32x4 pv1 = *(const f32x4*)(pts4 + 4 * r1);
            const float e00 = pv0[0] - s0[0] * rd0, e01 = pv0[1] - s0[1] * rd0, e02 = pv0[2] - s0[2] * rd0;
            const float e10 = pv1[0] - s1[0] * rd1, e11 = pv1[1] - s1[1] * rd1, e12 = pv1[2] - s1[2] * rd1;
            cd_s[wv32 + p0]      = sqrtf(e00 * e00 + e01 * e01 + e02 * e02);
            cd_s[wv32 + 16 + p0] = sqrtf(e10 * e10 + e11 * e11 + e12 * e12);
        }
    }

    // own-point normalized coords (lanes 0..31)
    if (lane < WPTS) {
        const int ipp = min(i0w + lane, n - 1);
        const f32x4 pv = *(const f32x4*)(pts4 + 4 * ipp);
        pts_s[(wv32 + lane) * 4 + 0] = (pv[0] - stats[0]) * rcpf(stats[3]);
        pts_s[(wv32 + lane) * 4 + 1] = (pv[1] - stats[1]) * rcpf(stats[4]);
        pts_s[(wv32 + lane) * 4 + 2] = (pv[2] - stats[2]) * rcpf(stats[5]);
    }

    // ============ Phase B: pipelined fp8 gather, 2 points per iteration ======
    {
        const int ul   = lane & 31;
        const int half = lane >> 5;
        // boundary-MLP weights: 4 hidden units per lane-column (shared by halves)
        float w1f[4], w1c[4], b1v[4], w2v[4];
        #pragma unroll
        for (int j = 0; j < 4; ++j) {
            int u = ul + 32 * j;
            w1f[j] = bd_w1[u]; w1c[j] = bd_w1[H + u];
            b1v[j] = bd_b1[u]; w2v[j] = bd_w2[u];
        }
        const float bb2 = bd_b2[0];

        unsigned cur[16], nxt[16];
        #pragma unroll
        for (int k = 0; k < K; ++k) {
            const int r = nb_w[half * K + k];
            cur[k] = xg[(size_t)r * 32 + ul];
        }
        for (int pr = 0; pr < 16; ++pr) {
            if (pr < 15) {
                #pragma unroll
                for (int k = 0; k < K; ++k) {
                    const int r = nb_w[((pr + 1) * 2 + half) * K + k];
                    nxt[k] = xg[(size_t)r * 32 + ul];
                }
            }
            float f0 = 0, f1 = 0, f2 = 0, f3 = 0;
            #pragma unroll
            for (int k = 0; k < K; ++k) {
                const unsigned u = cur[k];
                f0 += e5m2f(u); f1 += e5m2f(u >> 8);
                f2 += e5m2f(u >> 16); f3 += e5m2f(u >> 24);
            }
            const int p = 2 * pr + half;
            const float rden = rcpf(denom_s[wv32 + p]);
            f0 *= rden; f1 *= rden; f2 *= rden; f3 *= rden;
            short4v pk; pk[0] = f2bf(f0); pk[1] = f2bf(f1); pk[2] = f2bf(f2); pk[3] = f2bf(f3);
            *(short4v*)((short*)mf_s + (size_t)(wv32 + p) * (HSU * 2) + ul * 4) = pk;

            const int ipp = min(i0w + p, n - 1);
            const uint2 xv = *(const uint2*)(xb + (size_t)ipp * 64 + 2 * ul);
            const float d0 = bflo(xv.x) - f0, d1 = bfhi(xv.x) - f1;
            const float d2 = bflo(xv.y) - f2, d3 = bfhi(xv.y) - f3;
            float ss = d0 * d0 + d1 * d1 + d2 * d2 + d3 * d3;
            #pragma unroll
            for (int o = 16; o > 0; o >>= 1) ss += __shfl_xor(ss, o, 64);
            const float fd = sqrtf(ss);
            const float cd = cd_s[wv32 + p];
            float s = 0.0f;
            #pragma unroll
            for (int j = 0; j < 4; ++j)
                s += gelu_f(fd * w1f[j] + cd * w1c[j] + b1v[j]) * w2v[j];
            #pragma unroll
            for (int o = 16; o > 0; o >>= 1) s += __shfl_xor(s, o, 64);
            if (ul == 0) bd_s[wv32 + p] = sigm(s + bb2);
            #pragma unroll
            for (int k = 0; k < K; ++k) cur[k] = nxt[k];
        }
    }

    // ================= GEMM phases (2 groups of 16 points per wave) ==========
    const int pr0 = wv32 + m16, pr1 = wv32 + 16 + m16;
    const int ig0 = i0 + pr0,   ig1 = i0 + pr1;
    const int ip0 = min(ig0, n - 1), ip1 = min(ig1, n - 1);
    const unsigned* xr0  = xb + (size_t)ip0 * 64;
    const unsigned* xr1  = xb + (size_t)ip1 * 64;
    const unsigned* mfr0 = mf_s + pr0 * HSU;
    const unsigned* mfr1 = mf_s + pr1 * HSU;
    unsigned* hr0 = hid_s + pr0 * HSU;
    unsigned* hr1 = hid_s + pr1 * HSU;

    // ---- cp MLP: hidden from regs, cp2 GEMM -> ce into hid ----
    {
        const float px0 = pts_s[pr0 * 4], py0 = pts_s[pr0 * 4 + 1], pz0 = pts_s[pr0 * 4 + 2];
        const float px1 = pts_s[pr1 * 4], py1 = pts_s[pr1 * 4 + 1], pz1 = pts_s[pr1 * 4 + 2];
        f32x4 a0[8], a1[8];
        #pragma unroll
        for (int t = 0; t < 8; ++t) { a0[t] = (f32x4)0.0f; a1[t] = (f32x4)0.0f; }
        #pragma unroll
        for (int c = 0; c < 4; ++c) {
            short8 af0, af1;
            #pragma unroll
            for (int j = 0; j < 8; ++j) {
                const int hh = c * 32 + h4 * 8 + j;
                const float wa = cp_w1[hh], wb = cp_w1[H + hh], wc2 = cp_w1[2 * H + hh];
                const float bb = cp_b1[hh];
                af0[j] = f2bf(gelu_f(bb + px0 * wa + py0 * wb + pz0 * wc2));
                af1[j] = f2bf(gelu_f(bb + px1 * wa + py1 * wb + pz1 * wc2));
            }
            const short* wcp = wt + WT_CP2 + c * 4096 + lane * 8;
            #pragma unroll
            for (int t = 0; t < 8; ++t) {
                const short8 wf = *(const short8*)(wcp + t * 512);
                a0[t] = __builtin_amdgcn_mfma_f32_16x16x32_bf16(wf, af0, a0[t], 0, 0, 0);
                a1[t] = __builtin_amdgcn_mfma_f32_16x16x32_bf16(wf, af1, a1[t], 0, 0, 0);
            }
        }
        #pragma unroll
        for (int t = 0; t < 8; ++t) {
            const f32x4 bb = *(const f32x4*)(cp_b2 + t * 16 + h4 * 4);
            const f32x4 v0 = a0[t] + bb, v1 = a1[t] + bb;
            short4v pk0, pk1;
            #pragma unroll
            for (int r = 0; r < 4; ++r) { pk0[r] = f2bf(v0[r]); pk1[r] = f2bf(v1[r]); }
            *(short4v*)((short*)hr0 + t * 16 + h4 * 4) = pk0;
            *(short4v*)((short*)hr1 + t * 16 + h4 * 4) = pk1;
        }
    }

    const float bdp0 = bd_s[pr0], bdp1 = bd_s[pr1];

    // ---- mix1 (K=384: x | mf | ce) + rank-1 + bias, GELU -> hid ----
    {
        f32x4 a0[8], a1[8];
        #pragma unroll
        for (int t = 0; t < 8; ++t) { a0[t] = (f32x4)0.0f; a1[t] = (f32x4)0.0f; }
        #pragma unroll
        for (int c = 0; c < 12; ++c) {
            short8 af0, af1;
            if (c < 4) {
                af0 = *(const short8*)(xr0 + c * 16 + h4 * 4);
                af1 = *(const short8*)(xr1 + c * 16 + h4 * 4);
            } else if (c < 8) {
                af0 = *(const short8*)(mfr0 + (c - 4) * 16 + h4 * 4);
                af1 = *(const short8*)(mfr1 + (c - 4) * 16 + h4 * 4);
            } else {
                af0 = *(const short8*)(hr0 + (c - 8) * 16 + h4 * 4);
                af1 = *(const short8*)(hr1 + (c - 8) * 16 + h4 * 4);
            }
            const short* wmc = wt + WT_MIX + c * 4096 + lane * 8;
            #pragma unroll
            for (int t = 0; t < 8; ++t) {
                const short8 wf = *(const short8*)(wmc + t * 512);
                a0[t] = __builtin_amdgcn_mfma_f32_16x16x32_bf16(wf, af0, a0[t], 0, 0, 0);
                a1[t] = __builtin_amdgcn_mfma_f32_16x16x32_bf16(wf, af1, a1[t], 0, 0, 0);
            }
        }
        #pragma unroll
        for (int t = 0; t < 8; ++t) {
            const int col = t * 16 + h4 * 4;
            const f32x4 wb = *(const f32x4*)(mix_w1 + 256 * C + col);
            const f32x4 bb = *(const f32x4*)(mix_b1 + col);
            const f32x4 v0 = a0[t] + bdp0 * wb + bb;
            const f32x4 v1 = a1[t] + bdp1 * wb + bb;
            short4v pk0, pk1;
            #pragma unroll
            for (int r = 0; r < 4; ++r) { pk0[r] = f2bf(gelu_f(v0[r])); pk1[r] = f2bf(gelu_f(v1[r])); }
            *(short4v*)((short*)hr0 + col) = pk0;
            *(short4v*)((short*)hr1 + col) = pk1;
        }
    }

    // ---- mix2 -> refined (regs) ----
    f32x4 rf0[8], rf1[8];
    {
        #pragma unroll
        for (int t = 0; t < 8; ++t) { rf0[t] = (f32x4)0.0f; rf1[t] = (f32x4)0.0f; }
        #pragma unroll
        for (int c = 0; c < 4; ++c) {
            const short8 af0 = *(const short8*)(hr0 + c * 16 + h4 * 4);
            const short8 af1 = *(const short8*)(hr1 + c * 16 + h4 * 4);
            const short* wmc = wt + WT_MIX2 + c * 4096 + lane * 8;
            #pragma unroll
            for (int t = 0; t < 8; ++t) {
                const short8 wf = *(const short8*)(wmc + t * 512);
                rf0[t] = __builtin_amdgcn_mfma_f32_16x16x32_bf16(wf, af0, rf0[t], 0, 0, 0);
                rf1[t] = __builtin_amdgcn_mfma_f32_16x16x32_bf16(wf, af1, rf1[t], 0, 0, 0);
            }
        }
        #pragma unroll
        for (int t = 0; t < 8; ++t) {
            const f32x4 bb = *(const f32x4*)(mix_b2 + t * 16 + h4 * 4);
            rf0[t] += bb; rf1[t] += bb;
        }
    }

    // ---- gate1 (K=256: x | mf) + rank-1 + bias, GELU -> hid (overwrite) ----
    {
        f32x4 a0[8], a1[8];
        #pragma unroll
        for (int t = 0; t < 8; ++t) { a0[t] = (f32x4)0.0f; a1[t] = (f32x4)0.0f; }
        #pragma unroll
        for (int c = 0; c < 8; ++c) {
            short8 af0, af1;
            if (c < 4) {
                af0 = *(const short8*)(xr0 + c * 16 + h4 * 4);
                af1 = *(const short8*)(xr1 + c * 16 + h4 * 4);
            } else {
                af0 = *(const short8*)(mfr0 + (c - 4) * 16 + h4 * 4);
                af1 = *(const short8*)(mfr1 + (c - 4) * 16 + h4 * 4);
            }
            const short* wgc = wt + WT_GATE + c * 4096 + lane * 8;
            #pragma unroll
            for (int t = 0; t < 8; ++t) {
                const short8 wf = *(const short8*)(wgc + t * 512);
                a0[t] = __builtin_amdgcn_mfma_f32_16x16x32_bf16(wf, af0, a0[t], 0, 0, 0);
                a1[t] = __builtin_amdgcn_mfma_f32_16x16x32_bf16(wf, af1, a1[t], 0, 0, 0);
            }
        }
        #pragma unroll
        for (int t = 0; t < 8; ++t) {
            const int col = t * 16 + h4 * 4;
            const f32x4 wb = *(const f32x4*)(gate_w1 + 256 * C + col);
            const f32x4 bb = *(const f32x4*)(gate_b1 + col);
            const f32x4 v0 = a0[t] + bdp0 * wb + bb;
            const f32x4 v1 = a1[t] + bdp1 * wb + bb;
            short4v pk0, pk1;
            #pragma unroll
            for (int r = 0; r < 4; ++r) { pk0[r] = f2bf(gelu_f(v0[r])); pk1[r] = f2bf(gelu_f(v1[r])); }
            *(short4v*)((short*)hr0 + col) = pk0;
            *(short4v*)((short*)hr1 + col) = pk1;
        }
    }

    // ---- gate2 -> sigmoid * refined -> gr (overwrite hid) ----
    {
        f32x4 a0[8], a1[8];
        #pragma unroll
        for (int t = 0; t < 8; ++t) { a0[t] = (f32x4)0.0f; a1[t] = (f32x4)0.0f; }
        #pragma unroll
        for (int c = 0; c < 4; ++c) {
            const short8 af0 = *(const short8*)(hr0 + c * 16 + h4 * 4);
            const short8 af1 = *(const short8*)(hr1 + c * 16 + h4 * 4);
            const short* wgc = wt + WT_GATE2 + c * 4096 + lane * 8;
            #pragma unroll
            for (int t = 0; t < 8; ++t) {
                const short8 wf = *(const short8*)(wgc + t * 512);
                a0[t] = __builtin_amdgcn_mfma_f32_16x16x32_bf16(wf, af0, a0[t], 0, 0, 0);
                a1[t] = __builtin_amdgcn_mfma_f32_16x16x32_bf16(wf, af1, a1[t], 0, 0, 0);
            }
        }
        #pragma unroll
        for (int t = 0; t < 8; ++t) {
            const int col = t * 16 + h4 * 4;
            const f32x4 bb = *(const f32x4*)(gate_b2 + col);
            short4v pk0, pk1;
            #pragma unroll
            for (int r = 0; r < 4; ++r) {
                pk0[r] = f2bf(sigm(a0[t][r] + bb[r]) * rf0[t][r]);
                pk1[r] = f2bf(sigm(a1[t][r] + bb[r]) * rf1[t][r]);
            }
            *(short4v*)((short*)hr0 + col) = pk0;
            *(short4v*)((short*)hr1 + col) = pk1;
        }
    }

    // ---- out GEMM + bias + residual -> global store ----
    {
        f32x4 a0[8], a1[8];
        #pragma unroll
        for (int t = 0; t < 8; ++t) { a0[t] = (f32x4)0.0f; a1[t] = (f32x4)0.0f; }
        #pragma unroll
        for (int c = 0; c < 4; ++c) {
            const short8 af0 = *(const short8*)(hr0 + c * 16 + h4 * 4);
            const short8 af1 = *(const short8*)(hr1 + c * 16 + h4 * 4);
            const short* woc = wt + WT_OUT + c * 4096 + lane * 8;
            #pragma unroll
            for (int t = 0; t < 8; ++t) {
                const short8 wf = *(const short8*)(woc + t * 512);
                a0[t] = __builtin_amdgcn_mfma_f32_16x16x32_bf16(wf, af0, a0[t], 0, 0, 0);
                a1[t] = __builtin_amdgcn_mfma_f32_16x16x32_bf16(wf, af1, a1[t], 0, 0, 0);
            }
        }
        #pragma unroll
        for (int t = 0; t < 8; ++t) {
            const int col = t * 16 + h4 * 4;
            const f32x4 bb = *(const f32x4*)(out_b + col);
            const f32x4 fv0 = *(const f32x4*)(feats + (size_t)ip0 * C + col);
            const f32x4 fv1 = *(const f32x4*)(feats + (size_t)ip1 * C + col);
            const f32x4 v0 = a0[t] + bb + fv0;
            const f32x4 v1 = a1[t] + bb + fv1;
            if (ig0 < n) *(f32x4*)(out + (size_t)ig0 * C + col) = v0;
            if (ig1 < n) *(f32x4*)(out + (size_t)ig1 * C + col) = v1;
        }
    }
}

// ---------------------------------------------------------------------------
extern "C" void kernel_launch(void* const* d_in, const int* in_sizes, int n_in,
                              void* d_out, int out_size, void* d_ws, size_t ws_size,
                              hipStream_t stream)
{
    const float* feats     = (const float*)d_in[0];
    const float* points    = (const float*)d_in[1];
    const int*   neighbors = (const int*)d_in[2];
    const float* ln_g      = (const float*)d_in[3];
    const float* ln_b      = (const float*)d_in[4];
    const float* cp_w1     = (const float*)d_in[5];
    const float* cp_b1     = (const float*)d_in[6];
    const float* cp_w2     = (const float*)d_in[7];
    const float* cp_b2     = (const float*)d_in[8];
    const float* bd_w1     = (const float*)d_in[9];
    const float* bd_b1     = (const float*)d_in[10];
    const float* bd_w2     = (const float*)d_in[11];
    const float* bd_b2     = (const float*)d_in[12];
    const float* mix_w1    = (const float*)d_in[13];
    const float* mix_b1    = (const float*)d_in[14];
    const float* mix_w2    = (const float*)d_in[15];
    const float* mix_b2    = (const float*)d_in[16];
    const float* gate_w1   = (const float*)d_in[17];
    const float* gate_b1   = (const float*)d_in[18];
    const float* gate_w2   = (const float*)d_in[19];
    const float* gate_b2   = (const float*)d_in[20];
    const float* out_w     = (const float*)d_in[21];
    const float* out_b     = (const float*)d_in[22];
    float* out = (float*)d_out;
    (void)n_in; (void)out_size; (void)ws_size;

    const int n = in_sizes[0] / C;

    // ws layout: xb u32[(n+1)*64] | xg u16[(n+1)*64] | pts4 f32[(n+1)*4]
    //            | wt bf16[WT_TOTAL] | partial f32[NB2*9] | stats f32[6]
    char* base = (char*)d_ws;
    unsigned* xb        = (unsigned*)base;
    unsigned short* xg  = (unsigned short*)(base + (size_t)(n + 1) * 256);
    float* pts4         = (float*)(base + (size_t)(n + 1) * 256 + (size_t)(n + 1) * 128);
    short* wt           = (short*)((char*)pts4 + (size_t)(n + 1) * 16);
    float* partial      = (float*)((char*)wt + (size_t)WT_TOTAL * 2);
    float* stats        = partial + NB2 * 9;

    const int prep_blocks = 37 + (n + 256) / 256;
    prep_wt<<<prep_blocks, 256, 0, stream>>>(
        mix_w1, gate_w1, cp_w2, mix_w2, gate_w2, out_w, points,
        wt, xb + (size_t)n * 64, (unsigned*)(xg + (size_t)n * 64), pts4, n);
    ln_kernel<<<(n + 3) / 4, 256, 0, stream>>>(feats, ln_g, ln_b, xb, xg, n);
    pstat_partial<<<NB2, 256, 0, stream>>>(points, partial, n);
    pstat_final<<<1, 256, 0, stream>>>(partial, stats, n);
    main_kernel<<<(n + PB - 1) / PB, 256, 0, stream>>>(
        xb, (const unsigned*)xg, pts4, feats, neighbors, stats, wt,
        cp_w1, cp_b1, cp_b2, bd_w1, bd_b1, bd_w2, bd_b2,
        mix_w1, mix_b1, mix_b2, gate_w1, gate_b1, gate_b2,
        out_b, out, n);
}